// Round 10
// baseline (277.106 us; speedup 1.0000x reference)
//
#include <hip/hip_runtime.h>
#include <math.h>

typedef unsigned short u16;
typedef __attribute__((ext_vector_type(8))) short short8;
typedef __attribute__((ext_vector_type(4))) float floatx4;
typedef __attribute__((ext_vector_type(16))) float floatx16;
typedef __attribute__((ext_vector_type(4))) short sh4v;
typedef __attribute__((ext_vector_type(2))) unsigned uint2v;

union sh4u { sh4v v; u16 u[4]; };
union sh8u { short8 v; u16 u[8]; };
union sh8w { short8 v; unsigned w[4]; };

__device__ __forceinline__ floatx4 mfma16(short8 a, short8 b, floatx4 c) {
  return __builtin_amdgcn_mfma_f32_16x16x32_bf16(a, b, c, 0, 0, 0);
}
__device__ __forceinline__ floatx16 mfma32(short8 a, short8 b, floatx16 c) {
  return __builtin_amdgcn_mfma_f32_32x32x16_bf16(a, b, c, 0, 0, 0);
}

__device__ __forceinline__ floatx4 zero4() {
  floatx4 z = {0.f, 0.f, 0.f, 0.f};
  return z;
}
__device__ __forceinline__ floatx16 zero16() {
  floatx16 z;
#pragma unroll
  for (int i = 0; i < 16; i++) z[i] = 0.f;
  return z;
}

// raw hardware exp2 (single v_exp_f32; args are bounded attention logits)
__device__ __forceinline__ float hexp2(float x) {
  return __builtin_amdgcn_exp2f(x);
}

__device__ __forceinline__ u16 f2b(float f) {
  union { float f; unsigned u; } v; v.f = f;
  unsigned u = v.u;
  return (u16)((u + 0x7FFFu + ((u >> 16) & 1u)) >> 16);
}

__device__ __forceinline__ float b2f(u16 u) {
  union { unsigned u; float f; } v; v.u = ((unsigned)u) << 16;
  return v.f;
}

// packed-bf16 dword helpers: low element = low u16, high element = high u16
__device__ __forceinline__ float blo(unsigned w) {
  union { unsigned u; float f; } v; v.u = w << 16;
  return v.f;
}
__device__ __forceinline__ float bhi(unsigned w) {
  union { unsigned u; float f; } v; v.u = w & 0xFFFF0000u;
  return v.f;
}

__device__ __forceinline__ float gelu_exact(float x) {
  return 0.5f * x * (1.f + erff(x * 0.70710678118654752440f));
}

__device__ __forceinline__ unsigned pack2(float a, float b) {
  return (unsigned)f2b(a) | ((unsigned)f2b(b) << 16);
}

// truncating pack of two f32 -> two bf16 in one v_perm
__device__ __forceinline__ unsigned permpack(float p0, float p1) {
  return __builtin_amdgcn_perm(__float_as_uint(p1), __float_as_uint(p0), 0x07060302u);
}

// async global->LDS, 16B per lane: LDS dest = wave-uniform base + lane*16 (linear);
// global src is per-lane (pre-swizzled).
__device__ __forceinline__ void gload16(const u16* g, u16* l) {
  __builtin_amdgcn_global_load_lds(
      (const __attribute__((address_space(1))) unsigned*)(const void*)g,
      (__attribute__((address_space(3))) unsigned*)(void*)l, 16, 0, 0);
}

// ------------- fat kernel: weight transpose-convert (blocks 0..611) + LN1 (612..2659) -------------
__global__ __launch_bounds__(256) void tcln_kernel(
    const float* __restrict__ p0, const float* __restrict__ p1,
    const float* __restrict__ p2, const float* __restrict__ p3,
    const float* __restrict__ p4, const float* __restrict__ p5,
    const float* __restrict__ wknn,
    u16* __restrict__ o0, u16* __restrict__ o1, u16* __restrict__ o2,
    u16* __restrict__ o3, u16* __restrict__ o4, u16* __restrict__ o5,
    u16* __restrict__ wcT,
    const float* __restrict__ x, const float* __restrict__ g,
    const float* __restrict__ bia, u16* __restrict__ nx) {
  __shared__ u16 L[64][66];
  int t = blockIdx.x, tid = threadIdx.x;
  if (t >= 612) {
    // ---- LN1: one wave per row ----
    int wave = tid >> 6, lane = tid & 63;
    int row = (t - 612) * 4 + wave;
    const float* xr = x + (size_t)row * 384;
    float v[6];
    float s = 0.f;
#pragma unroll
    for (int j = 0; j < 6; j++) { v[j] = xr[lane + 64 * j]; s += v[j]; }
#pragma unroll
    for (int off = 32; off > 0; off >>= 1) s += __shfl_xor(s, off);
    float mu = s * (1.f / 384.f);
    float ss = 0.f;
#pragma unroll
    for (int j = 0; j < 6; j++) { float d = v[j] - mu; ss += d * d; }
#pragma unroll
    for (int off = 32; off > 0; off >>= 1) ss += __shfl_xor(ss, off);
    float rstd = rsqrtf(ss * (1.f / 384.f) + 1e-5f);
    u16* orow = nx + (size_t)row * 384;
#pragma unroll
    for (int j = 0; j < 6; j++) {
      int d = lane + 64 * j;
      orow[d] = f2b((v[j] - mu) * rstd * g[d] + bia[d]);
    }
    return;
  }
  if (t >= 540) {
    t -= 540;                       // wcT: 6 k-tiles x 12 j-tiles
    int tk = t / 12, tn = t % 12;
    int k0 = tk * 64, j0 = tn * 64;
#pragma unroll
    for (int i = 0; i < 4; i++) {
      int c = tid + 256 * i;
      int r = c >> 4, c4 = (c & 15) * 4;
      floatx4 v;
      if (j0 < 384) {
        v = *(const floatx4*)(wknn + (size_t)(k0 + r) * 384 + j0 + c4);
      } else {
        floatx4 a = *(const floatx4*)(wknn + (size_t)(384 + k0 + r) * 384 + (j0 - 384) + c4);
        floatx4 b = *(const floatx4*)(wknn + (size_t)(k0 + r) * 384 + (j0 - 384) + c4);
        v = a - b;
      }
      *(unsigned*)&L[r][c4]     = pack2(v[0], v[1]);
      *(unsigned*)&L[r][c4 + 2] = pack2(v[2], v[3]);
    }
    __syncthreads();
#pragma unroll
    for (int i = 0; i < 2; i++) {
      int c = tid + 256 * i;
      int nn = c >> 3, k8 = (c & 7) * 8;
      sh8u pk;
#pragma unroll
      for (int j = 0; j < 8; j++) pk.u[j] = L[k8 + j][nn];
      *(short8*)(wcT + (size_t)(j0 + nn) * 384 + k0 + k8) = pk.v;
    }
    return;
  }
  const float* src; u16* dst; int Kd, Nd, tk, tn;
  if      (t < 108) { src = p0; dst = o0; Kd = 384;  Nd = 1152; tk = t / 18; tn = t % 18; }
  else if (t < 144) { src = p1; dst = o1; Kd = 384;  Nd = 384;  t -= 108; tk = t / 6;  tn = t % 6; }
  else if (t < 216) { src = p2; dst = o2; Kd = 768;  Nd = 384;  t -= 144; tk = t / 6;  tn = t % 6; }
  else if (t < 252) { src = p3; dst = o3; Kd = 384;  Nd = 384;  t -= 216; tk = t / 6;  tn = t % 6; }
  else if (t < 396) { src = p4; dst = o4; Kd = 384;  Nd = 1536; t -= 252; tk = t / 24; tn = t % 24; }
  else              { src = p5; dst = o5; Kd = 1536; Nd = 384;  t -= 396; tk = t / 6;  tn = t % 6; }
  int k0 = tk * 64, n0 = tn * 64;
#pragma unroll
  for (int i = 0; i < 4; i++) {
    int c = tid + 256 * i;
    int r = c >> 4, c4 = (c & 15) * 4;
    floatx4 v = *(const floatx4*)(src + (size_t)(k0 + r) * Nd + n0 + c4);
    *(unsigned*)&L[r][c4]     = pack2(v[0], v[1]);
    *(unsigned*)&L[r][c4 + 2] = pack2(v[2], v[3]);
  }
  __syncthreads();
#pragma unroll
  for (int i = 0; i < 2; i++) {
    int c = tid + 256 * i;
    int nn = c >> 3, k8 = (c & 7) * 8;
    sh8u pk;
#pragma unroll
    for (int j = 0; j < 8; j++) pk.u[j] = L[k8 + j][nn];
    *(short8*)(dst + (size_t)(n0 + nn) * Kd + k0 + k8) = pk.v;
  }
}

// ---------------- LayerNorm (bf16 in -> bf16 out), one wave per row of 384 ----------------
__global__ __launch_bounds__(256) void lnb_kernel(const u16* __restrict__ x,
                                                  const float* __restrict__ g,
                                                  const float* __restrict__ bia,
                                                  u16* __restrict__ out) {
  int wave = threadIdx.x >> 6, lane = threadIdx.x & 63;
  int row = blockIdx.x * 4 + wave;
  const u16* xr = x + (size_t)row * 384;
  float v[6];
  float s = 0.f;
#pragma unroll
  for (int j = 0; j < 6; j++) { v[j] = b2f(xr[lane + 64 * j]); s += v[j]; }
#pragma unroll
  for (int off = 32; off > 0; off >>= 1) s += __shfl_xor(s, off);
  float mu = s * (1.f / 384.f);
  float ss = 0.f;
#pragma unroll
  for (int j = 0; j < 6; j++) { float d = v[j] - mu; ss += d * d; }
#pragma unroll
  for (int off = 32; off > 0; off >>= 1) ss += __shfl_xor(ss, off);
  float rstd = rsqrtf(ss * (1.f / 384.f) + 1e-5f);
  u16* orow = out + (size_t)row * 384;
#pragma unroll
  for (int j = 0; j < 6; j++) {
    int d = lane + 64 * j;
    orow[d] = f2b((v[j] - mu) * rstd * g[d] + bia[d]);
  }
}

// ---------------- gemm64: MRx128N tile, BK=64, global_load_lds staging ----------------
// m97 structure: 2 barriers/kt, single LDS buffer, async global->LDS (no reg staging).
// Linear LDS rows [64] u16; source pre-swizzled by slot^row XOR; reads apply same XOR
// (rule #21 both-sides involution) -> 2-way bank conflicts (free).
// EPI: 3 gelu(+bias) -> bf16 | 4 gate -> bf16 | 7 +bias + bf16-resid -> f32
//      8 fused qkv+GB: col<1152 -> qkv (Q pre-scale, V^T scatter), else GBb bf16
template <int EPI, int MR>
__global__ __launch_bounds__(256) void gemm64_kernel(
    const u16* __restrict__ A0, const u16* __restrict__ A1, int Ksplit,
    const u16* __restrict__ BwT, const u16* __restrict__ BwT2, int N, int K,
    const float* __restrict__ bias,
    float* __restrict__ outF, u16* __restrict__ outB, u16* __restrict__ outB2,
    const u16* __restrict__ eA16, const u16* __restrict__ eK16,
    const float* __restrict__ eX, u16* __restrict__ outV) {
  const int MT = MR / 16;   // m-tiles per wave
  __shared__ u16 As[MR][64];
  __shared__ u16 Bs[128][64];
  int tid = threadIdx.x;
  int lane = tid & 63, w = tid >> 6, quad = lane >> 4, l16 = lane & 15;
  int n0 = blockIdx.x * 128, m0 = blockIdx.y * MR;
  const u16* Bsrc = BwT;
  int nbase = n0;
  if (EPI == 8 && n0 >= 1152) { Bsrc = BwT2; nbase = n0 - 1152; }
  floatx4 acc[MT][2];
#pragma unroll
  for (int i = 0; i < MT; i++)
#pragma unroll
    for (int j = 0; j < 2; j++) acc[i][j] = zero4();

  int r8 = lane >> 3, s8 = lane & 7;
  int ksw = (s8 ^ r8) * 8;   // pre-swizzled k-offset (u16) for this lane's LDS slot
  auto stage = [&](int k0) {
    const u16* Ap;
    int kk, sA;
    if (k0 < Ksplit) { Ap = A0; kk = k0; sA = Ksplit; }
    else             { Ap = A1; kk = k0 - Ksplit; sA = K - Ksplit; }
#pragma unroll
    for (int p = 0; p < MR / 32; p++) {
      int rw = p * 32 + w * 8;   // wave-uniform row base; HW adds lane*16B (= +r8 rows, slot s8)
      gload16(Ap + (size_t)(m0 + rw + r8) * sA + kk + ksw, &As[rw][0]);
    }
#pragma unroll
    for (int p = 0; p < 4; p++) {
      int rw = p * 32 + w * 8;
      gload16(Bsrc + (size_t)(nbase + rw + r8) * K + k0 + ksw, &Bs[rw][0]);
    }
  };
  stage(0);
  int x7 = l16 & 7;
  int co0 = (quad ^ x7) * 8;         // kh=0 physical slot offset (u16)
  int co1 = ((quad + 4) ^ x7) * 8;   // kh=1
  int iters = K >> 6;
  for (int kt = 0; kt < iters; kt++) {
    __syncthreads();   // drains vmcnt: tile kt resident in LDS
#pragma unroll
    for (int kh = 0; kh < 2; kh++) {
      int co = kh ? co1 : co0;
      short8 af[MT], bfr[2];
#pragma unroll
      for (int mt = 0; mt < MT; mt++)
        af[mt] = *(const short8*)&As[mt * 16 + l16][co];
#pragma unroll
      for (int nt = 0; nt < 2; nt++)
        bfr[nt] = *(const short8*)&Bs[w * 32 + nt * 16 + l16][co];
#pragma unroll
      for (int mt = 0; mt < MT; mt++)
#pragma unroll
        for (int nt = 0; nt < 2; nt++)
          acc[mt][nt] = mfma16(af[mt], bfr[nt], acc[mt][nt]);
    }
    __syncthreads();   // all reads done before next overwrite
    if (kt + 1 < iters) stage((kt + 1) * 64);
  }

#pragma unroll
  for (int mt = 0; mt < MT; mt++)
#pragma unroll
    for (int nt = 0; nt < 2; nt++) {
      int col = n0 + w * 32 + nt * 16 + l16;
      int row0 = m0 + mt * 16 + quad * 4;
      if (EPI == 8) {
        if (col < 1152) {
          float sc = (col < 384) ? 0.18033688011112042f : 1.f;  // Q * 0.125*log2(e)
          sh4u pk;
#pragma unroll
          for (int r = 0; r < 4; r++) {
            u16 bv = f2b(acc[mt][nt][r] * sc);
            outB[(size_t)(row0 + r) * 1152 + col] = bv;
            pk.u[r] = bv;
          }
          if (col >= 768) {
            int b = row0 >> 11, n = row0 & 2047;
            int hd = col - 768;
            *(sh4v*)(outV + ((size_t)(b * 6 + (hd >> 6)) * 64 + (hd & 63)) * 2048 + n) = pk.v;
          }
        } else {
#pragma unroll
          for (int r = 0; r < 4; r++)
            outB2[(size_t)(row0 + r) * 768 + (col - 1152)] = f2b(acc[mt][nt][r]);
        }
      } else {
#pragma unroll
        for (int r = 0; r < 4; r++) {
          size_t rc = (size_t)(row0 + r) * N + col;
          float v = acc[mt][nt][r];
          if (EPI == 3) {
            outB[rc] = f2b(gelu_exact(v + bias[col]));
          } else if (EPI == 4) {
            float gte = 1.f / (1.f + hexp2(-1.44269504088896f * (v + bias[col])));
            float fu = (1.f - gte) * b2f(eA16[rc]) + gte * b2f(eK16[rc]);
            outB[rc] = f2b(eX[rc] + fu);
          } else if (EPI == 7) {
            outF[rc] = v + bias[col] + b2f(eA16[rc]);
          }
        }
      }
    }
}

// ------- fat kernel: attention (blocks 0..1535, 4 splits) + EdgeConv knn (1536..3583) -------
// attn: 4 waves x 32 q-rows, 32x32 MFMA, P in-register via permpack + permlane32_swap,
//       inline VALU row-sum. LDS double-buffered K/V tiles, one barrier per kt.
__global__ __launch_bounds__(256) void attnknn_kernel(
    const u16* __restrict__ qkv, const u16* __restrict__ Vt,
    u16* __restrict__ OPb, float* __restrict__ LS,
    const u16* __restrict__ GBb, const int* __restrict__ kidx,
    const float* __restrict__ bknn, u16* __restrict__ knn_bf) {
  __shared__ u16 Ks[2][64][72];    // K tile [key][dim], double-buffered
  __shared__ u16 Vts[2][64][72];   // V^T tile [dim][key], double-buffered
  int bid = blockIdx.x, tid = threadIdx.x;
  int lane = tid & 63, w = tid >> 6;
  if (bid >= 1536) {
    // ---- EdgeConv gather + max over K=8, then lrelu once (lrelu monotone, base k-invariant) ----
    int row = (bid - 1536) * 4 + w;  // 0..8191
    int b = row >> 11, n = row & 2047;
    // lane element map: e0..e3 = 4*lane.. (dwords 2*lane,2*lane+1), e4,e5 = 256+2*lane (dword 128+lane)
    const unsigned* browp = (const unsigned*)(GBb + (size_t)row * 768 + 384);
    uint2v bw01 = *(const uint2v*)(browp + 2 * lane);
    unsigned bw2 = browp[128 + lane];
    floatx4 bk4 = *(const floatx4*)(bknn + 4 * lane);
    float bk40 = bknn[256 + 2 * lane], bk41 = bknn[256 + 2 * lane + 1];
    int gi[8];
#pragma unroll
    for (int kk = 0; kk < 8; kk++) gi[kk] = kidx[(b * 8 + kk) * 2048 + n];
    float mx[6];
#pragma unroll
    for (int e = 0; e < 6; e++) mx[e] = -1e30f;
#pragma unroll
    for (int kk = 0; kk < 8; kk++) {
      const unsigned* gp = (const unsigned*)(GBb + (size_t)gi[kk] * 768);
      uint2v g01 = *(const uint2v*)(gp + 2 * lane);
      unsigned g2 = gp[128 + lane];
      mx[0] = fmaxf(mx[0], blo(g01[0]));
      mx[1] = fmaxf(mx[1], bhi(g01[0]));
      mx[2] = fmaxf(mx[2], blo(g01[1]));
      mx[3] = fmaxf(mx[3], bhi(g01[1]));
      mx[4] = fmaxf(mx[4], blo(g2));
      mx[5] = fmaxf(mx[5], bhi(g2));
    }
    float vv[6];
    vv[0] = mx[0] + blo(bw01[0]) + bk4[0];
    vv[1] = mx[1] + bhi(bw01[0]) + bk4[1];
    vv[2] = mx[2] + blo(bw01[1]) + bk4[2];
    vv[3] = mx[3] + bhi(bw01[1]) + bk4[3];
    vv[4] = mx[4] + blo(bw2) + bk40;
    vv[5] = mx[5] + bhi(bw2) + bk41;
#pragma unroll
    for (int e = 0; e < 6; e++) vv[e] = fmaxf(vv[e], 0.2f * vv[e]);
    unsigned* op = (unsigned*)(knn_bf + (size_t)row * 384);
    uint2v ow;
    ow[0] = pack2(vv[0], vv[1]);
    ow[1] = pack2(vv[2], vv[3]);
    *(uint2v*)(op + 2 * lane) = ow;
    op[128 + lane] = pack2(vv[4], vv[5]);
    return;
  }
  // XCD-aware swizzle: the 16 q-tile blocks sharing one (b,h,split) K/V panel land on one XCD
  int vb = (bid & 7) * 192 + (bid >> 3);   // bijective: 1536 = 8*192
  int split = vb / 384;
  int rr = vb - split * 384;
  int bh = rr >> 4, b = bh / 6, h = bh % 6;
  int q0 = (rr & 15) * 128;
  int ql = lane & 31, h5 = lane >> 5;
  const u16* qbase = qkv + (size_t)b * 2048 * 1152 + h * 64;
  const u16* kbase = qbase + 384 + (size_t)split * 512 * 1152;
  const u16* vtb = Vt + (size_t)bh * 64 * 2048 + split * 512;
  int qrow = q0 + w * 32 + ql;
  // Q B-fragments: lane holds Q[qrow][16*s + 8*h5 + 0..7]  (Q pre-scaled by 0.125*log2e)
  short8 qB[4];
#pragma unroll
  for (int s = 0; s < 4; s++)
    qB[s] = *(const short8*)(qbase + (size_t)qrow * 1152 + s * 16 + h5 * 8);
  floatx16 O[2];
  O[0] = zero16(); O[1] = zero16();
  float accLs = 0.f;  // per-lane partial row-sum (16-key subset per t; halves combined at epilogue)

  int rb = tid >> 3, c8 = (tid & 7) * 8;
  short8 rk[2], rv[2];
  rk[0] = *(const short8*)(kbase + (size_t)rb * 1152 + c8);
  rk[1] = *(const short8*)(kbase + (size_t)(rb + 32) * 1152 + c8);
  rv[0] = *(const short8*)(vtb + (size_t)rb * 2048 + c8);
  rv[1] = *(const short8*)(vtb + (size_t)(rb + 32) * 2048 + c8);

  int cur = 0;
  for (int kt = 0; kt < 8; kt++) {
    // write this tile into buf[cur]; safe vs readers of buf[cur^1] (previous iter)
    *(short8*)&Ks[cur][rb][c8] = rk[0];
    *(short8*)&Ks[cur][rb + 32][c8] = rk[1];
    *(short8*)&Vts[cur][rb][c8] = rv[0];
    *(short8*)&Vts[cur][rb + 32][c8] = rv[1];
    __syncthreads();  // single barrier per kt: tile visible to all waves
    if (kt < 7) {
      int key0 = (kt + 1) * 64;
      rk[0] = *(const short8*)(kbase + (size_t)(key0 + rb) * 1152 + c8);
      rk[1] = *(const short8*)(kbase + (size_t)(key0 + rb + 32) * 1152 + c8);
      rv[0] = *(const short8*)(vtb + (size_t)rb * 2048 + key0 + c8);
      rv[1] = *(const short8*)(vtb + (size_t)(rb + 32) * 2048 + key0 + c8);
    }
    // per key-half t: S^T (32 keys x 32 q) in registers, exp2 inline, pack, then PV
#pragma unroll
    for (int t = 0; t < 2; t++) {
      floatx16 st = zero16();
#pragma unroll
      for (int s = 0; s < 4; s++) {
        short8 aK = *(const short8*)&Ks[cur][32 * t + ql][16 * s + 8 * h5];
        st = mfma32(aK, qB[s], st);
      }
      // key(r) = 32t + (r&3) + 8*(r>>2) + 4*h5; W[j] packs keys (koff(j), koff(j)+1),
      // koff = {0,2,8,10,16,18,24,26}. Row-sum accumulated inline (no e[] array).
      unsigned W[8];
#pragma unroll
      for (int j = 0; j < 8; j++) {
        float e0 = hexp2(st[2 * j]), e1 = hexp2(st[2 * j + 1]);
        accLs += e0 + e1;
        W[j] = permpack(e0, e1);
      }
      // PV: two 16-key chunks per t. b-frag words via permlane32_swap of (+8)-offset pairs.
#pragma unroll
      for (int c = 0; c < 2; c++) {
        int kk = 2 * t + c;
        uint2v s0 = __builtin_amdgcn_permlane32_swap(W[4 * c], W[4 * c + 2], false, false);
        uint2v s1 = __builtin_amdgcn_permlane32_swap(W[4 * c + 1], W[4 * c + 3], false, false);
        sh8w pb_;
        pb_.w[0] = s0[0];
        pb_.w[1] = s1[0];
        pb_.w[2] = s0[1];
        pb_.w[3] = s1[1];
        short8 aV0 = *(const short8*)&Vts[cur][ql][16 * kk + 8 * h5];
        short8 aV1 = *(const short8*)&Vts[cur][32 + ql][16 * kk + 8 * h5];
        O[0] = mfma32(aV0, pb_.v, O[0]);
        O[1] = mfma32(aV1, pb_.v, O[1]);
      }
    }
    cur ^= 1;
  }
  // epilogue: unnormalized bf16 partials + f32 row-sum
  // O^T layout: q = ql, dim = 32*d + (r&3) + 8*(r>>2) + 4*h5
  u16* orow = OPb + (size_t)split * 8192 * 384 + (size_t)(b * 2048 + qrow) * 384 + h * 64;
#pragma unroll
  for (int d = 0; d < 2; d++)
#pragma unroll
    for (int rq = 0; rq < 4; rq++) {
      sh4u pk;
#pragma unroll
      for (int r3 = 0; r3 < 4; r3++) pk.u[r3] = f2b(O[d][4 * rq + r3]);
      *(sh4v*)(orow + 32 * d + 8 * rq + 4 * h5) = pk.v;
    }
  // combine h5 halves: lane<32 adds partner (lane+32)'s partial via permlane32_swap out1
  uint2v sw = __builtin_amdgcn_permlane32_swap(__float_as_uint(accLs), __float_as_uint(accLs),
                                               false, false);
  if (lane < 32) LS[split * 8192 + b * 2048 + qrow] = accLs + __uint_as_float(sw[1]);
}

// ---------------- proj: 64Mx128N GEMM on unnormalized split-sum, normalize in epilogue ----------------
__global__ __launch_bounds__(256) void projc_kernel(
    const u16* __restrict__ OPb, const float* __restrict__ LS,
    const u16* __restrict__ BwT, const float* __restrict__ bias,
    u16* __restrict__ outB) {
  __shared__ u16 As[64][72];
  __shared__ u16 Bs[128][72];
  int tid = threadIdx.x;
  int lane = tid & 63, w = tid >> 6, quad = lane >> 4, l16 = lane & 15;
  int n0 = blockIdx.x * 128, m0 = blockIdx.y * 64;
  int ra = tid >> 3, ca = (tid & 7) * 8;
  const size_t SP = (size_t)8192 * 384;
  floatx4 acc[4][2];
#pragma unroll
  for (int i = 0; i < 4; i++)
#pragma unroll
    for (int j = 0; j < 2; j++) acc[i][j] = zero4();

  short8 pa[2], pb[4];
  auto loadAB = [&](int k0) {
#pragma unroll
    for (int i = 0; i < 2; i++) {
      const u16* p = OPb + (size_t)(m0 + ra + 32 * i) * 384 + k0 + ca;
      sh8u a0, a1, a2, a3, pk;
      a0.v = *(const short8*)p;
      a1.v = *(const short8*)(p + SP);
      a2.v = *(const short8*)(p + 2 * SP);
      a3.v = *(const short8*)(p + 3 * SP);
#pragma unroll
      for (int j = 0; j < 8; j++)
        pk.u[j] = f2b((b2f(a0.u[j]) + b2f(a1.u[j])) + (b2f(a2.u[j]) + b2f(a3.u[j])));
      pa[i] = pk.v;
    }
#pragma unroll
    for (int i = 0; i < 4; i++)
      pb[i] = *(const short8*)(BwT + (size_t)(n0 + ra + 32 * i) * 384 + k0 + ca);
  };
  loadAB(0);
  for (int kt = 0; kt < 6; kt++) {
    __syncthreads();
    *(short8*)&As[ra][ca] = pa[0];
    *(short8*)&As[ra + 32][ca] = pa[1];
#pragma unroll
    for (int i = 0; i < 4; i++) *(short8*)&Bs[ra + 32 * i][ca] = pb[i];
    __syncthreads();
    if (kt < 5) loadAB((kt + 1) * 64);
#pragma unroll
    for (int kh = 0; kh < 2; kh++) {
      short8 af[4], bfr[2];
#pragma unroll
      for (int mt = 0; mt < 4; mt++)
        af[mt] = *(const short8*)&As[mt * 16 + l16][kh * 32 + quad * 8];
#pragma unroll
      for (int nt = 0; nt < 2; nt++)
        bfr[nt] = *(const short8*)&Bs[w * 32 + nt * 16 + l16][kh * 32 + quad * 8];
#pragma unroll
      for (int mt = 0; mt < 4; mt++)
#pragma unroll
        for (int nt = 0; nt < 2; nt++)
          acc[mt][nt] = mfma16(af[mt], bfr[nt], acc[mt][nt]);
    }
  }
#pragma unroll
  for (int mt = 0; mt < 4; mt++) {
    int row0 = m0 + mt * 16 + quad * 4;
    float rl[4];
#pragma unroll
    for (int r = 0; r < 4; r++) {
      int gr = row0 + r;
      rl[r] = 1.f / ((LS[gr] + LS[8192 + gr]) + (LS[16384 + gr] + LS[24576 + gr]));
    }
#pragma unroll
    for (int nt = 0; nt < 2; nt++) {
      int col = n0 + w * 32 + nt * 16 + l16;
#pragma unroll
      for (int r = 0; r < 4; r++)
        outB[(size_t)(row0 + r) * 384 + col] = f2b(acc[mt][nt][r] * rl[r] + bias[col]);
    }
  }
}

// ---------------- launch ----------------
extern "C" void kernel_launch(void* const* d_in, const int* in_sizes, int n_in,
                              void* d_out, int out_size, void* d_ws, size_t ws_size,
                              hipStream_t stream) {
  const float* x    = (const float*)d_in[0];
  const int* kidx   = (const int*)d_in[1];
  const float* ln1g = (const float*)d_in[2];
  const float* ln1b = (const float*)d_in[3];
  const float* wqkv = (const float*)d_in[4];
  const float* wproj= (const float*)d_in[5];
  const float* bproj= (const float*)d_in[6];
  const float* wknn = (const float*)d_in[7];
  const float* bknn = (const float*)d_in[8];
  const float* wg1  = (const float*)d_in[9];
  const float* bg1  = (const float*)d_in[10];
  const float* wg2  = (const float*)d_in[11];
  const float* bg2  = (const float*)d_in[12];
  const float* ln2g = (const float*)d_in[13];
  const float* ln2b = (const float*)d_in[14];
  const float* wfc1 = (const float*)d_in[15];
  const float* bfc1 = (const float*)d_in[16];
  const float* wfc2 = (const float*)d_in[17];
  const float* bfc2 = (const float*)d_in[18];
  float* out = (float*)d_out;

  const int M = 8192;
  char* ws = (char*)d_ws;
  size_t off = 0;
  auto alloc = [&](size_t bytes) -> char* {
    char* p = ws + off;
    off += (bytes + 255) & ~(size_t)255;
    return p;
  };
  u16* nx_bf    = (u16*)alloc((size_t)M * 384 * 2);
  u16* qkv_bf   = (u16*)alloc((size_t)M * 1152 * 2);   // + attn_bf reused as h_bf
  u16* attn_bf  = (u16*)alloc((size_t)M * 384 * 2);
  u16* GBb      = (u16*)alloc((size_t)M * 768 * 2);    // [G | base] bf16
  u16* knn_bf   = (u16*)alloc((size_t)M * 384 * 2);
  u16* x2b      = (u16*)alloc((size_t)M * 384 * 2);
  u16* t1_bf    = (u16*)alloc((size_t)M * 384 * 2);
  u16* nx2_bf   = (u16*)alloc((size_t)M * 384 * 2);
  u16* Vt_b     = (u16*)alloc((size_t)24 * 64 * 2048 * 2);
  u16* OPb      = (u16*)alloc((size_t)4 * M * 384 * 2);  // attn split partials (bf16)
  float* LS     = (float*)alloc((size_t)4 * M * 4);
  u16* wqkvT    = (u16*)alloc((size_t)1152 * 384 * 2);
  u16* wprojT   = (u16*)alloc(384 * 384 * 2);
  u16* wcT      = (u16*)alloc((size_t)768 * 384 * 2);
  u16* wg1T     = (u16*)alloc((size_t)384 * 768 * 2);
  u16* wg2T     = (u16*)alloc(384 * 384 * 2);
  u16* wfc1T    = (u16*)alloc((size_t)1536 * 384 * 2);
  u16* wfc2T    = (u16*)alloc((size_t)384 * 1536 * 2);
  u16* h_bf     = qkv_bf;  // 8192x1536 bf16 over dead qkv(18.9MB)+attn_bf(6.3MB) regions

  // weight prep + LN1 (one fat launch)
  tcln_kernel<<<2660, 256, 0, stream>>>(wqkv, wproj, wg1, wg2, wfc1, wfc2, wknn,
                                        wqkvT, wprojT, wg1T, wg2T, wfc1T, wfc2T, wcT,
                                        x, ln1g, ln1b, nx_bf);
  // fused qkv + GB: [qkv | GBb] = nx @ [wqkvT | wcT]  (1920 blocks)
  gemm64_kernel<8, 64><<<dim3(15, 128), 256, 0, stream>>>(nx_bf, nx_bf, 384, wqkvT, wcT, 1920, 384,
                                                          nullptr, nullptr, qkv_bf, GBb,
                                                          nullptr, nullptr, nullptr, Vt_b);
  // attention (key-split=4, 32x32 MFMA + permlane P, LDS dbuf 1-barrier) + knn gather-max
  attnknn_kernel<<<3584, 256, 0, stream>>>(qkv_bf, Vt_b, OPb, LS,
                                           GBb, kidx, bknn, knn_bf);
  // proj: combine(OP0..OP3) @ wprojT, normalize+bias in epilogue  (384 blocks)
  projc_kernel<<<dim3(3, 128), 256, 0, stream>>>(OPb, LS, wprojT, bproj, attn_bf);
  // gate hidden: gelu([attn|knn] @ w_g1 + b_g1) -> bf16  (384 blocks)
  gemm64_kernel<3, 64><<<dim3(3, 128), 256, 0, stream>>>(attn_bf, knn_bf, 384, wg1T, nullptr, 384, 768,
                                                         bg1, nullptr, t1_bf, nullptr,
                                                         nullptr, nullptr, nullptr, nullptr);
  // gate + fuse + residual: x2b = bf16(x + (1-g)*attn + g*knn)  (384 blocks)
  gemm64_kernel<4, 64><<<dim3(3, 128), 256, 0, stream>>>(t1_bf, t1_bf, 384, wg2T, nullptr, 384, 384,
                                                         bg2, nullptr, x2b, nullptr,
                                                         attn_bf, knn_bf, x, nullptr);
  // LN2 (bf16 in)
  lnb_kernel<<<2048, 256, 0, stream>>>(x2b, ln2g, ln2b, nx2_bf);
  // fc1: gelu(nx2 @ w_fc1 + b_fc1) -> bf16  (1536 blocks)
  gemm64_kernel<3, 64><<<dim3(12, 128), 256, 0, stream>>>(nx2_bf, nx2_bf, 384, wfc1T, nullptr, 1536, 384,
                                                          bfc1, nullptr, h_bf, nullptr,
                                                          nullptr, nullptr, nullptr, nullptr);
  // fc2: out = x2 + h @ w_fc2 + b_fc2  (384 blocks)
  gemm64_kernel<7, 64><<<dim3(3, 128), 256, 0, stream>>>(h_bf, h_bf, 1536, wfc2T, nullptr, 384, 1536,
                                                         bfc2, out, nullptr, nullptr,
                                                         x2b, nullptr, nullptr, nullptr);
  (void)in_sizes; (void)n_in; (void)out_size; (void)ws_size;
}

// Round 11
// 258.639 us; speedup vs baseline: 1.0714x; 1.0714x over previous
//
#include <hip/hip_runtime.h>
#include <math.h>

typedef unsigned short u16;
typedef __attribute__((ext_vector_type(8))) short short8;
typedef __attribute__((ext_vector_type(4))) float floatx4;
typedef __attribute__((ext_vector_type(16))) float floatx16;
typedef __attribute__((ext_vector_type(4))) short sh4v;
typedef __attribute__((ext_vector_type(2))) unsigned uint2v;

union sh4u { sh4v v; u16 u[4]; };
union sh8u { short8 v; u16 u[8]; };
union sh8w { short8 v; unsigned w[4]; };

__device__ __forceinline__ floatx4 mfma16(short8 a, short8 b, floatx4 c) {
  return __builtin_amdgcn_mfma_f32_16x16x32_bf16(a, b, c, 0, 0, 0);
}
__device__ __forceinline__ floatx16 mfma32(short8 a, short8 b, floatx16 c) {
  return __builtin_amdgcn_mfma_f32_32x32x16_bf16(a, b, c, 0, 0, 0);
}

__device__ __forceinline__ floatx4 zero4() {
  floatx4 z = {0.f, 0.f, 0.f, 0.f};
  return z;
}
__device__ __forceinline__ floatx16 zero16() {
  floatx16 z;
#pragma unroll
  for (int i = 0; i < 16; i++) z[i] = 0.f;
  return z;
}

// raw hardware exp2 (single v_exp_f32; args are bounded attention logits)
__device__ __forceinline__ float hexp2(float x) {
  return __builtin_amdgcn_exp2f(x);
}

__device__ __forceinline__ u16 f2b(float f) {
  union { float f; unsigned u; } v; v.f = f;
  unsigned u = v.u;
  return (u16)((u + 0x7FFFu + ((u >> 16) & 1u)) >> 16);
}

__device__ __forceinline__ float b2f(u16 u) {
  union { unsigned u; float f; } v; v.u = ((unsigned)u) << 16;
  return v.f;
}

// packed-bf16 dword helpers: low element = low u16, high element = high u16
__device__ __forceinline__ float blo(unsigned w) {
  union { unsigned u; float f; } v; v.u = w << 16;
  return v.f;
}
__device__ __forceinline__ float bhi(unsigned w) {
  union { unsigned u; float f; } v; v.u = w & 0xFFFF0000u;
  return v.f;
}

__device__ __forceinline__ float gelu_exact(float x) {
  return 0.5f * x * (1.f + erff(x * 0.70710678118654752440f));
}

__device__ __forceinline__ unsigned pack2(float a, float b) {
  return (unsigned)f2b(a) | ((unsigned)f2b(b) << 16);
}

// truncating pack of two f32 -> two bf16 in one v_perm
__device__ __forceinline__ unsigned permpack(float p0, float p1) {
  return __builtin_amdgcn_perm(__float_as_uint(p1), __float_as_uint(p0), 0x07060302u);
}

// ------------- fat kernel: weight transpose-convert (blocks 0..611) + LN1 (612..2659) -------------
__global__ __launch_bounds__(256) void tcln_kernel(
    const float* __restrict__ p0, const float* __restrict__ p1,
    const float* __restrict__ p2, const float* __restrict__ p3,
    const float* __restrict__ p4, const float* __restrict__ p5,
    const float* __restrict__ wknn,
    u16* __restrict__ o0, u16* __restrict__ o1, u16* __restrict__ o2,
    u16* __restrict__ o3, u16* __restrict__ o4, u16* __restrict__ o5,
    u16* __restrict__ wcT,
    const float* __restrict__ x, const float* __restrict__ g,
    const float* __restrict__ bia, u16* __restrict__ nx) {
  __shared__ u16 L[64][66];
  int t = blockIdx.x, tid = threadIdx.x;
  if (t >= 612) {
    // ---- LN1: one wave per row ----
    int wave = tid >> 6, lane = tid & 63;
    int row = (t - 612) * 4 + wave;
    const float* xr = x + (size_t)row * 384;
    float v[6];
    float s = 0.f;
#pragma unroll
    for (int j = 0; j < 6; j++) { v[j] = xr[lane + 64 * j]; s += v[j]; }
#pragma unroll
    for (int off = 32; off > 0; off >>= 1) s += __shfl_xor(s, off);
    float mu = s * (1.f / 384.f);
    float ss = 0.f;
#pragma unroll
    for (int j = 0; j < 6; j++) { float d = v[j] - mu; ss += d * d; }
#pragma unroll
    for (int off = 32; off > 0; off >>= 1) ss += __shfl_xor(ss, off);
    float rstd = rsqrtf(ss * (1.f / 384.f) + 1e-5f);
    u16* orow = nx + (size_t)row * 384;
#pragma unroll
    for (int j = 0; j < 6; j++) {
      int d = lane + 64 * j;
      orow[d] = f2b((v[j] - mu) * rstd * g[d] + bia[d]);
    }
    return;
  }
  if (t >= 540) {
    t -= 540;                       // wcT: 6 k-tiles x 12 j-tiles
    int tk = t / 12, tn = t % 12;
    int k0 = tk * 64, j0 = tn * 64;
#pragma unroll
    for (int i = 0; i < 4; i++) {
      int c = tid + 256 * i;
      int r = c >> 4, c4 = (c & 15) * 4;
      floatx4 v;
      if (j0 < 384) {
        v = *(const floatx4*)(wknn + (size_t)(k0 + r) * 384 + j0 + c4);
      } else {
        floatx4 a = *(const floatx4*)(wknn + (size_t)(384 + k0 + r) * 384 + (j0 - 384) + c4);
        floatx4 b = *(const floatx4*)(wknn + (size_t)(k0 + r) * 384 + (j0 - 384) + c4);
        v = a - b;
      }
      *(unsigned*)&L[r][c4]     = pack2(v[0], v[1]);
      *(unsigned*)&L[r][c4 + 2] = pack2(v[2], v[3]);
    }
    __syncthreads();
#pragma unroll
    for (int i = 0; i < 2; i++) {
      int c = tid + 256 * i;
      int nn = c >> 3, k8 = (c & 7) * 8;
      sh8u pk;
#pragma unroll
      for (int j = 0; j < 8; j++) pk.u[j] = L[k8 + j][nn];
      *(short8*)(wcT + (size_t)(j0 + nn) * 384 + k0 + k8) = pk.v;
    }
    return;
  }
  const float* src; u16* dst; int Kd, Nd, tk, tn;
  if      (t < 108) { src = p0; dst = o0; Kd = 384;  Nd = 1152; tk = t / 18; tn = t % 18; }
  else if (t < 144) { src = p1; dst = o1; Kd = 384;  Nd = 384;  t -= 108; tk = t / 6;  tn = t % 6; }
  else if (t < 216) { src = p2; dst = o2; Kd = 768;  Nd = 384;  t -= 144; tk = t / 6;  tn = t % 6; }
  else if (t < 252) { src = p3; dst = o3; Kd = 384;  Nd = 384;  t -= 216; tk = t / 6;  tn = t % 6; }
  else if (t < 396) { src = p4; dst = o4; Kd = 384;  Nd = 1536; t -= 252; tk = t / 24; tn = t % 24; }
  else              { src = p5; dst = o5; Kd = 1536; Nd = 384;  t -= 396; tk = t / 6;  tn = t % 6; }
  int k0 = tk * 64, n0 = tn * 64;
#pragma unroll
  for (int i = 0; i < 4; i++) {
    int c = tid + 256 * i;
    int r = c >> 4, c4 = (c & 15) * 4;
    floatx4 v = *(const floatx4*)(src + (size_t)(k0 + r) * Nd + n0 + c4);
    *(unsigned*)&L[r][c4]     = pack2(v[0], v[1]);
    *(unsigned*)&L[r][c4 + 2] = pack2(v[2], v[3]);
  }
  __syncthreads();
#pragma unroll
  for (int i = 0; i < 2; i++) {
    int c = tid + 256 * i;
    int nn = c >> 3, k8 = (c & 7) * 8;
    sh8u pk;
#pragma unroll
    for (int j = 0; j < 8; j++) pk.u[j] = L[k8 + j][nn];
    *(short8*)(dst + (size_t)(n0 + nn) * Kd + k0 + k8) = pk.v;
  }
}

// ---------------- LayerNorm (bf16 in -> bf16 out), one wave per row of 384 ----------------
__global__ __launch_bounds__(256) void lnb_kernel(const u16* __restrict__ x,
                                                  const float* __restrict__ g,
                                                  const float* __restrict__ bia,
                                                  u16* __restrict__ out) {
  int wave = threadIdx.x >> 6, lane = threadIdx.x & 63;
  int row = blockIdx.x * 4 + wave;
  const u16* xr = x + (size_t)row * 384;
  float v[6];
  float s = 0.f;
#pragma unroll
  for (int j = 0; j < 6; j++) { v[j] = b2f(xr[lane + 64 * j]); s += v[j]; }
#pragma unroll
  for (int off = 32; off > 0; off >>= 1) s += __shfl_xor(s, off);
  float mu = s * (1.f / 384.f);
  float ss = 0.f;
#pragma unroll
  for (int j = 0; j < 6; j++) { float d = v[j] - mu; ss += d * d; }
#pragma unroll
  for (int off = 32; off > 0; off >>= 1) ss += __shfl_xor(ss, off);
  float rstd = rsqrtf(ss * (1.f / 384.f) + 1e-5f);
  u16* orow = out + (size_t)row * 384;
#pragma unroll
  for (int j = 0; j < 6; j++) {
    int d = lane + 64 * j;
    orow[d] = f2b((v[j] - mu) * rstd * g[d] + bia[d]);
  }
}

// ---------------- gemm64: 64Mx128N tile, BK=64, reg-prefetch dbuf ----------------
// EPI: 3 gelu(+bias) -> bf16 | 4 gate -> bf16 | 7 +bias + bf16-resid -> f32
//      8 fused qkv+GB: col<1152 -> qkv (Q pre-scale, V^T scatter), else GBb bf16
template <int EPI>
__global__ __launch_bounds__(256) void gemm64_kernel(
    const u16* __restrict__ A0, const u16* __restrict__ A1, int Ksplit,
    const u16* __restrict__ BwT, const u16* __restrict__ BwT2, int N, int K,
    const float* __restrict__ bias,
    float* __restrict__ outF, u16* __restrict__ outB, u16* __restrict__ outB2,
    const u16* __restrict__ eA16, const u16* __restrict__ eK16,
    const float* __restrict__ eX, u16* __restrict__ outV) {
  __shared__ u16 As[64][72];
  __shared__ u16 Bs[128][72];
  int tid = threadIdx.x;
  int lane = tid & 63, w = tid >> 6, quad = lane >> 4, l16 = lane & 15;
  int n0 = blockIdx.x * 128, m0 = blockIdx.y * 64;
  int ra = tid >> 3, ca = (tid & 7) * 8;
  const u16* Bsrc = BwT;
  int nbase = n0;
  if (EPI == 8 && n0 >= 1152) { Bsrc = BwT2; nbase = n0 - 1152; }
  floatx4 acc[4][2];
#pragma unroll
  for (int i = 0; i < 4; i++)
#pragma unroll
    for (int j = 0; j < 2; j++) acc[i][j] = zero4();

  short8 pa[2], pb[4];
  auto loadAB = [&](int k0) {
    const u16* Ap;
    int kk, sA;
    if (k0 < Ksplit) { Ap = A0; kk = k0; sA = Ksplit; }
    else             { Ap = A1; kk = k0 - Ksplit; sA = K - Ksplit; }
    pa[0] = *(const short8*)(Ap + (size_t)(m0 + ra) * sA + kk + ca);
    pa[1] = *(const short8*)(Ap + (size_t)(m0 + ra + 32) * sA + kk + ca);
#pragma unroll
    for (int i = 0; i < 4; i++)
      pb[i] = *(const short8*)(Bsrc + (size_t)(nbase + ra + 32 * i) * K + k0 + ca);
  };
  loadAB(0);
  int iters = K >> 6;
  for (int kt = 0; kt < iters; kt++) {
    __syncthreads();
    *(short8*)&As[ra][ca] = pa[0];
    *(short8*)&As[ra + 32][ca] = pa[1];
#pragma unroll
    for (int i = 0; i < 4; i++) *(short8*)&Bs[ra + 32 * i][ca] = pb[i];
    __syncthreads();
    if (kt + 1 < iters) loadAB((kt + 1) * 64);
#pragma unroll
    for (int kh = 0; kh < 2; kh++) {
      short8 af[4], bfr[2];
#pragma unroll
      for (int mt = 0; mt < 4; mt++)
        af[mt] = *(const short8*)&As[mt * 16 + l16][kh * 32 + quad * 8];
#pragma unroll
      for (int nt = 0; nt < 2; nt++)
        bfr[nt] = *(const short8*)&Bs[w * 32 + nt * 16 + l16][kh * 32 + quad * 8];
#pragma unroll
      for (int mt = 0; mt < 4; mt++)
#pragma unroll
        for (int nt = 0; nt < 2; nt++)
          acc[mt][nt] = mfma16(af[mt], bfr[nt], acc[mt][nt]);
    }
  }

#pragma unroll
  for (int mt = 0; mt < 4; mt++)
#pragma unroll
    for (int nt = 0; nt < 2; nt++) {
      int col = n0 + w * 32 + nt * 16 + l16;
      int row0 = m0 + mt * 16 + quad * 4;
      if (EPI == 8) {
        if (col < 1152) {
          float sc = (col < 384) ? 0.18033688011112042f : 1.f;  // Q * 0.125*log2(e)
          sh4u pk;
#pragma unroll
          for (int r = 0; r < 4; r++) {
            u16 bv = f2b(acc[mt][nt][r] * sc);
            outB[(size_t)(row0 + r) * 1152 + col] = bv;
            pk.u[r] = bv;
          }
          if (col >= 768) {
            int b = row0 >> 11, n = row0 & 2047;
            int hd = col - 768;
            *(sh4v*)(outV + ((size_t)(b * 6 + (hd >> 6)) * 64 + (hd & 63)) * 2048 + n) = pk.v;
          }
        } else {
#pragma unroll
          for (int r = 0; r < 4; r++)
            outB2[(size_t)(row0 + r) * 768 + (col - 1152)] = f2b(acc[mt][nt][r]);
        }
      } else {
#pragma unroll
        for (int r = 0; r < 4; r++) {
          size_t rc = (size_t)(row0 + r) * N + col;
          float v = acc[mt][nt][r];
          if (EPI == 3) {
            outB[rc] = f2b(gelu_exact(v + bias[col]));
          } else if (EPI == 4) {
            float gte = 1.f / (1.f + hexp2(-1.44269504088896f * (v + bias[col])));
            float fu = (1.f - gte) * b2f(eA16[rc]) + gte * b2f(eK16[rc]);
            outB[rc] = f2b(eX[rc] + fu);
          } else if (EPI == 7) {
            outF[rc] = v + bias[col] + b2f(eA16[rc]);
          }
        }
      }
    }
}

// ------- fat kernel: attention (blocks 0..1535, 4 splits) + EdgeConv knn (1536..3583) -------
// attn: 4 waves x 32 q-rows, 32x32 MFMA, P in-register via permpack + permlane32_swap,
//       inline VALU row-sum. LDS double-buffered K/V tiles, one barrier per kt.
__global__ __launch_bounds__(256) void attnknn_kernel(
    const u16* __restrict__ qkv, const u16* __restrict__ Vt,
    u16* __restrict__ OPb, float* __restrict__ LS,
    const u16* __restrict__ GBb, const int* __restrict__ kidx,
    const float* __restrict__ bknn, u16* __restrict__ knn_bf) {
  __shared__ u16 Ks[2][64][72];    // K tile [key][dim], double-buffered
  __shared__ u16 Vts[2][64][72];   // V^T tile [dim][key], double-buffered
  int bid = blockIdx.x, tid = threadIdx.x;
  int lane = tid & 63, w = tid >> 6;
  if (bid >= 1536) {
    // ---- EdgeConv gather + max over K=8, then lrelu once (lrelu monotone, base k-invariant) ----
    int row = (bid - 1536) * 4 + w;  // 0..8191
    int b = row >> 11, n = row & 2047;
    // lane element map: e0..e3 = 4*lane.. (dwords 2*lane,2*lane+1), e4,e5 = 256+2*lane (dword 128+lane)
    const unsigned* browp = (const unsigned*)(GBb + (size_t)row * 768 + 384);
    uint2v bw01 = *(const uint2v*)(browp + 2 * lane);
    unsigned bw2 = browp[128 + lane];
    floatx4 bk4 = *(const floatx4*)(bknn + 4 * lane);
    float bk40 = bknn[256 + 2 * lane], bk41 = bknn[256 + 2 * lane + 1];
    int gi[8];
#pragma unroll
    for (int kk = 0; kk < 8; kk++) gi[kk] = kidx[(b * 8 + kk) * 2048 + n];
    float mx[6];
#pragma unroll
    for (int e = 0; e < 6; e++) mx[e] = -1e30f;
#pragma unroll
    for (int kk = 0; kk < 8; kk++) {
      const unsigned* gp = (const unsigned*)(GBb + (size_t)gi[kk] * 768);
      uint2v g01 = *(const uint2v*)(gp + 2 * lane);
      unsigned g2 = gp[128 + lane];
      mx[0] = fmaxf(mx[0], blo(g01[0]));
      mx[1] = fmaxf(mx[1], bhi(g01[0]));
      mx[2] = fmaxf(mx[2], blo(g01[1]));
      mx[3] = fmaxf(mx[3], bhi(g01[1]));
      mx[4] = fmaxf(mx[4], blo(g2));
      mx[5] = fmaxf(mx[5], bhi(g2));
    }
    float vv[6];
    vv[0] = mx[0] + blo(bw01[0]) + bk4[0];
    vv[1] = mx[1] + bhi(bw01[0]) + bk4[1];
    vv[2] = mx[2] + blo(bw01[1]) + bk4[2];
    vv[3] = mx[3] + bhi(bw01[1]) + bk4[3];
    vv[4] = mx[4] + blo(bw2) + bk40;
    vv[5] = mx[5] + bhi(bw2) + bk41;
#pragma unroll
    for (int e = 0; e < 6; e++) vv[e] = fmaxf(vv[e], 0.2f * vv[e]);
    unsigned* op = (unsigned*)(knn_bf + (size_t)row * 384);
    uint2v ow;
    ow[0] = pack2(vv[0], vv[1]);
    ow[1] = pack2(vv[2], vv[3]);
    *(uint2v*)(op + 2 * lane) = ow;
    op[128 + lane] = pack2(vv[4], vv[5]);
    return;
  }
  // XCD-aware swizzle: the 16 q-tile blocks sharing one (b,h,split) K/V panel land on one XCD
  int vb = (bid & 7) * 192 + (bid >> 3);   // bijective: 1536 = 8*192
  int split = vb / 384;
  int rr = vb - split * 384;
  int bh = rr >> 4, b = bh / 6, h = bh % 6;
  int q0 = (rr & 15) * 128;
  int ql = lane & 31, h5 = lane >> 5;
  const u16* qbase = qkv + (size_t)b * 2048 * 1152 + h * 64;
  const u16* kbase = qbase + 384 + (size_t)split * 512 * 1152;
  const u16* vtb = Vt + (size_t)bh * 64 * 2048 + split * 512;
  int qrow = q0 + w * 32 + ql;
  // Q B-fragments: lane holds Q[qrow][16*s + 8*h5 + 0..7]  (Q pre-scaled by 0.125*log2e)
  short8 qB[4];
#pragma unroll
  for (int s = 0; s < 4; s++)
    qB[s] = *(const short8*)(qbase + (size_t)qrow * 1152 + s * 16 + h5 * 8);
  floatx16 O[2];
  O[0] = zero16(); O[1] = zero16();
  float accLs = 0.f;  // per-lane partial row-sum (16-key subset per t; halves combined at epilogue)

  int rb = tid >> 3, c8 = (tid & 7) * 8;
  short8 rk[2], rv[2];
  rk[0] = *(const short8*)(kbase + (size_t)rb * 1152 + c8);
  rk[1] = *(const short8*)(kbase + (size_t)(rb + 32) * 1152 + c8);
  rv[0] = *(const short8*)(vtb + (size_t)rb * 2048 + c8);
  rv[1] = *(const short8*)(vtb + (size_t)(rb + 32) * 2048 + c8);

  int cur = 0;
  for (int kt = 0; kt < 8; kt++) {
    // write this tile into buf[cur]; safe vs readers of buf[cur^1] (previous iter)
    *(short8*)&Ks[cur][rb][c8] = rk[0];
    *(short8*)&Ks[cur][rb + 32][c8] = rk[1];
    *(short8*)&Vts[cur][rb][c8] = rv[0];
    *(short8*)&Vts[cur][rb + 32][c8] = rv[1];
    __syncthreads();  // single barrier per kt: tile visible to all waves
    if (kt < 7) {
      int key0 = (kt + 1) * 64;
      rk[0] = *(const short8*)(kbase + (size_t)(key0 + rb) * 1152 + c8);
      rk[1] = *(const short8*)(kbase + (size_t)(key0 + rb + 32) * 1152 + c8);
      rv[0] = *(const short8*)(vtb + (size_t)rb * 2048 + key0 + c8);
      rv[1] = *(const short8*)(vtb + (size_t)(rb + 32) * 2048 + key0 + c8);
    }
    // per key-half t: S^T (32 keys x 32 q) in registers, exp2 inline, pack, then PV
#pragma unroll
    for (int t = 0; t < 2; t++) {
      floatx16 st = zero16();
#pragma unroll
      for (int s = 0; s < 4; s++) {
        short8 aK = *(const short8*)&Ks[cur][32 * t + ql][16 * s + 8 * h5];
        st = mfma32(aK, qB[s], st);
      }
      // key(r) = 32t + (r&3) + 8*(r>>2) + 4*h5; W[j] packs keys (koff(j), koff(j)+1),
      // koff = {0,2,8,10,16,18,24,26}. Row-sum accumulated inline (no e[] array).
      unsigned W[8];
#pragma unroll
      for (int j = 0; j < 8; j++) {
        float e0 = hexp2(st[2 * j]), e1 = hexp2(st[2 * j + 1]);
        accLs += e0 + e1;
        W[j] = permpack(e0, e1);
      }
      // PV: two 16-key chunks per t. b-frag words via permlane32_swap of (+8)-offset pairs.
#pragma unroll
      for (int c = 0; c < 2; c++) {
        int kk = 2 * t + c;
        uint2v s0 = __builtin_amdgcn_permlane32_swap(W[4 * c], W[4 * c + 2], false, false);
        uint2v s1 = __builtin_amdgcn_permlane32_swap(W[4 * c + 1], W[4 * c + 3], false, false);
        sh8w pb_;
        pb_.w[0] = s0[0];
        pb_.w[1] = s1[0];
        pb_.w[2] = s0[1];
        pb_.w[3] = s1[1];
        short8 aV0 = *(const short8*)&Vts[cur][ql][16 * kk + 8 * h5];
        short8 aV1 = *(const short8*)&Vts[cur][32 + ql][16 * kk + 8 * h5];
        O[0] = mfma32(aV0, pb_.v, O[0]);
        O[1] = mfma32(aV1, pb_.v, O[1]);
      }
    }
    cur ^= 1;
  }
  // epilogue: unnormalized bf16 partials + f32 row-sum
  // O^T layout: q = ql, dim = 32*d + (r&3) + 8*(r>>2) + 4*h5
  u16* orow = OPb + (size_t)split * 8192 * 384 + (size_t)(b * 2048 + qrow) * 384 + h * 64;
#pragma unroll
  for (int d = 0; d < 2; d++)
#pragma unroll
    for (int rq = 0; rq < 4; rq++) {
      sh4u pk;
#pragma unroll
      for (int r3 = 0; r3 < 4; r3++) pk.u[r3] = f2b(O[d][4 * rq + r3]);
      *(sh4v*)(orow + 32 * d + 8 * rq + 4 * h5) = pk.v;
    }
  // combine h5 halves: lane<32 adds partner (lane+32)'s partial via permlane32_swap out1
  uint2v sw = __builtin_amdgcn_permlane32_swap(__float_as_uint(accLs), __float_as_uint(accLs),
                                               false, false);
  if (lane < 32) LS[split * 8192 + b * 2048 + qrow] = accLs + __uint_as_float(sw[1]);
}

// ---------------- proj: 64Mx128N GEMM on unnormalized split-sum, normalize in epilogue ----------------
__global__ __launch_bounds__(256) void projc_kernel(
    const u16* __restrict__ OPb, const float* __restrict__ LS,
    const u16* __restrict__ BwT, const float* __restrict__ bias,
    u16* __restrict__ outB) {
  __shared__ u16 As[64][72];
  __shared__ u16 Bs[128][72];
  int tid = threadIdx.x;
  int lane = tid & 63, w = tid >> 6, quad = lane >> 4, l16 = lane & 15;
  int n0 = blockIdx.x * 128, m0 = blockIdx.y * 64;
  int ra = tid >> 3, ca = (tid & 7) * 8;
  const size_t SP = (size_t)8192 * 384;
  floatx4 acc[4][2];
#pragma unroll
  for (int i = 0; i < 4; i++)
#pragma unroll
    for (int j = 0; j < 2; j++) acc[i][j] = zero4();

  short8 pa[2], pb[4];
  auto loadAB = [&](int k0) {
#pragma unroll
    for (int i = 0; i < 2; i++) {
      const u16* p = OPb + (size_t)(m0 + ra + 32 * i) * 384 + k0 + ca;
      sh8u a0, a1, a2, a3, pk;
      a0.v = *(const short8*)p;
      a1.v = *(const short8*)(p + SP);
      a2.v = *(const short8*)(p + 2 * SP);
      a3.v = *(const short8*)(p + 3 * SP);
#pragma unroll
      for (int j = 0; j < 8; j++)
        pk.u[j] = f2b((b2f(a0.u[j]) + b2f(a1.u[j])) + (b2f(a2.u[j]) + b2f(a3.u[j])));
      pa[i] = pk.v;
    }
#pragma unroll
    for (int i = 0; i < 4; i++)
      pb[i] = *(const short8*)(BwT + (size_t)(n0 + ra + 32 * i) * 384 + k0 + ca);
  };
  loadAB(0);
  for (int kt = 0; kt < 6; kt++) {
    __syncthreads();
    *(short8*)&As[ra][ca] = pa[0];
    *(short8*)&As[ra + 32][ca] = pa[1];
#pragma unroll
    for (int i = 0; i < 4; i++) *(short8*)&Bs[ra + 32 * i][ca] = pb[i];
    __syncthreads();
    if (kt < 5) loadAB((kt + 1) * 64);
#pragma unroll
    for (int kh = 0; kh < 2; kh++) {
      short8 af[4], bfr[2];
#pragma unroll
      for (int mt = 0; mt < 4; mt++)
        af[mt] = *(const short8*)&As[mt * 16 + l16][kh * 32 + quad * 8];
#pragma unroll
      for (int nt = 0; nt < 2; nt++)
        bfr[nt] = *(const short8*)&Bs[w * 32 + nt * 16 + l16][kh * 32 + quad * 8];
#pragma unroll
      for (int mt = 0; mt < 4; mt++)
#pragma unroll
        for (int nt = 0; nt < 2; nt++)
          acc[mt][nt] = mfma16(af[mt], bfr[nt], acc[mt][nt]);
    }
  }
#pragma unroll
  for (int mt = 0; mt < 4; mt++) {
    int row0 = m0 + mt * 16 + quad * 4;
    float rl[4];
#pragma unroll
    for (int r = 0; r < 4; r++) {
      int gr = row0 + r;
      rl[r] = 1.f / ((LS[gr] + LS[8192 + gr]) + (LS[16384 + gr] + LS[24576 + gr]));
    }
#pragma unroll
    for (int nt = 0; nt < 2; nt++) {
      int col = n0 + w * 32 + nt * 16 + l16;
#pragma unroll
      for (int r = 0; r < 4; r++)
        outB[(size_t)(row0 + r) * 384 + col] = f2b(acc[mt][nt][r] * rl[r] + bias[col]);
    }
  }
}

// ---------------- launch ----------------
extern "C" void kernel_launch(void* const* d_in, const int* in_sizes, int n_in,
                              void* d_out, int out_size, void* d_ws, size_t ws_size,
                              hipStream_t stream) {
  const float* x    = (const float*)d_in[0];
  const int* kidx   = (const int*)d_in[1];
  const float* ln1g = (const float*)d_in[2];
  const float* ln1b = (const float*)d_in[3];
  const float* wqkv = (const float*)d_in[4];
  const float* wproj= (const float*)d_in[5];
  const float* bproj= (const float*)d_in[6];
  const float* wknn = (const float*)d_in[7];
  const float* bknn = (const float*)d_in[8];
  const float* wg1  = (const float*)d_in[9];
  const float* bg1  = (const float*)d_in[10];
  const float* wg2  = (const float*)d_in[11];
  const float* bg2  = (const float*)d_in[12];
  const float* ln2g = (const float*)d_in[13];
  const float* ln2b = (const float*)d_in[14];
  const float* wfc1 = (const float*)d_in[15];
  const float* bfc1 = (const float*)d_in[16];
  const float* wfc2 = (const float*)d_in[17];
  const float* bfc2 = (const float*)d_in[18];
  float* out = (float*)d_out;

  const int M = 8192;
  char* ws = (char*)d_ws;
  size_t off = 0;
  auto alloc = [&](size_t bytes) -> char* {
    char* p = ws + off;
    off += (bytes + 255) & ~(size_t)255;
    return p;
  };
  u16* nx_bf    = (u16*)alloc((size_t)M * 384 * 2);
  u16* qkv_bf   = (u16*)alloc((size_t)M * 1152 * 2);   // + attn_bf reused as h_bf
  u16* attn_bf  = (u16*)alloc((size_t)M * 384 * 2);
  u16* GBb      = (u16*)alloc((size_t)M * 768 * 2);    // [G | base] bf16
  u16* knn_bf   = (u16*)alloc((size_t)M * 384 * 2);
  u16* x2b      = (u16*)alloc((size_t)M * 384 * 2);
  u16* t1_bf    = (u16*)alloc((size_t)M * 384 * 2);
  u16* nx2_bf   = (u16*)alloc((size_t)M * 384 * 2);
  u16* Vt_b     = (u16*)alloc((size_t)24 * 64 * 2048 * 2);
  u16* OPb      = (u16*)alloc((size_t)4 * M * 384 * 2);  // attn split partials (bf16)
  float* LS     = (float*)alloc((size_t)4 * M * 4);
  u16* wqkvT    = (u16*)alloc((size_t)1152 * 384 * 2);
  u16* wprojT   = (u16*)alloc(384 * 384 * 2);
  u16* wcT      = (u16*)alloc((size_t)768 * 384 * 2);
  u16* wg1T     = (u16*)alloc((size_t)384 * 768 * 2);
  u16* wg2T     = (u16*)alloc(384 * 384 * 2);
  u16* wfc1T    = (u16*)alloc((size_t)1536 * 384 * 2);
  u16* wfc2T    = (u16*)alloc((size_t)384 * 1536 * 2);
  u16* h_bf     = qkv_bf;  // 8192x1536 bf16 over dead qkv(18.9MB)+attn_bf(6.3MB) regions

  // weight prep + LN1 (one fat launch)
  tcln_kernel<<<2660, 256, 0, stream>>>(wqkv, wproj, wg1, wg2, wfc1, wfc2, wknn,
                                        wqkvT, wprojT, wg1T, wg2T, wfc1T, wfc2T, wcT,
                                        x, ln1g, ln1b, nx_bf);
  // fused qkv + GB: [qkv | GBb] = nx @ [wqkvT | wcT]  (1920 blocks)
  gemm64_kernel<8><<<dim3(15, 128), 256, 0, stream>>>(nx_bf, nx_bf, 384, wqkvT, wcT, 1920, 384,
                                                      nullptr, nullptr, qkv_bf, GBb,
                                                      nullptr, nullptr, nullptr, Vt_b);
  // attention (key-split=4, 32x32 MFMA + permlane P, LDS dbuf 1-barrier) + knn gather-max
  attnknn_kernel<<<3584, 256, 0, stream>>>(qkv_bf, Vt_b, OPb, LS,
                                           GBb, kidx, bknn, knn_bf);
  // proj: combine(OP0..OP3) @ wprojT, normalize+bias in epilogue  (384 blocks)
  projc_kernel<<<dim3(3, 128), 256, 0, stream>>>(OPb, LS, wprojT, bproj, attn_bf);
  // gate hidden: gelu([attn|knn] @ w_g1 + b_g1) -> bf16  (384 blocks)
  gemm64_kernel<3><<<dim3(3, 128), 256, 0, stream>>>(attn_bf, knn_bf, 384, wg1T, nullptr, 384, 768,
                                                     bg1, nullptr, t1_bf, nullptr,
                                                     nullptr, nullptr, nullptr, nullptr);
  // gate + fuse + residual: x2b = bf16(x + (1-g)*attn + g*knn)  (384 blocks)
  gemm64_kernel<4><<<dim3(3, 128), 256, 0, stream>>>(t1_bf, t1_bf, 384, wg2T, nullptr, 384, 384,
                                                     bg2, nullptr, x2b, nullptr,
                                                     attn_bf, knn_bf, x, nullptr);
  // LN2 (bf16 in)
  lnb_kernel<<<2048, 256, 0, stream>>>(x2b, ln2g, ln2b, nx2_bf);
  // fc1: gelu(nx2 @ w_fc1 + b_fc1) -> bf16  (1536 blocks)
  gemm64_kernel<3><<<dim3(12, 128), 256, 0, stream>>>(nx2_bf, nx2_bf, 384, wfc1T, nullptr, 1536, 384,
                                                      bfc1, nullptr, h_bf, nullptr,
                                                      nullptr, nullptr, nullptr, nullptr);
  // fc2: out = x2 + h @ w_fc2 + b_fc2  (384 blocks)
  gemm64_kernel<7><<<dim3(3, 128), 256, 0, stream>>>(h_bf, h_bf, 1536, wfc2T, nullptr, 384, 1536,
                                                     bfc2, out, nullptr, nullptr,
                                                     x2b, nullptr, nullptr, nullptr);
  (void)in_sizes; (void)n_in; (void)out_size; (void)ws_size;
}

// Round 12
// 254.531 us; speedup vs baseline: 1.0887x; 1.0161x over previous
//
#include <hip/hip_runtime.h>
#include <math.h>

typedef unsigned short u16;
typedef __attribute__((ext_vector_type(8))) short short8;
typedef __attribute__((ext_vector_type(4))) float floatx4;
typedef __attribute__((ext_vector_type(16))) float floatx16;
typedef __attribute__((ext_vector_type(4))) short sh4v;
typedef __attribute__((ext_vector_type(2))) unsigned uint2v;

union sh4u { sh4v v; u16 u[4]; };
union sh8u { short8 v; u16 u[8]; };
union sh8w { short8 v; unsigned w[4]; };

__device__ __forceinline__ floatx4 mfma16(short8 a, short8 b, floatx4 c) {
  return __builtin_amdgcn_mfma_f32_16x16x32_bf16(a, b, c, 0, 0, 0);
}
__device__ __forceinline__ floatx16 mfma32(short8 a, short8 b, floatx16 c) {
  return __builtin_amdgcn_mfma_f32_32x32x16_bf16(a, b, c, 0, 0, 0);
}

__device__ __forceinline__ floatx4 zero4() {
  floatx4 z = {0.f, 0.f, 0.f, 0.f};
  return z;
}
__device__ __forceinline__ floatx16 zero16() {
  floatx16 z;
#pragma unroll
  for (int i = 0; i < 16; i++) z[i] = 0.f;
  return z;
}

// raw hardware exp2 (single v_exp_f32; args are bounded attention logits)
__device__ __forceinline__ float hexp2(float x) {
  return __builtin_amdgcn_exp2f(x);
}

__device__ __forceinline__ u16 f2b(float f) {
  union { float f; unsigned u; } v; v.f = f;
  unsigned u = v.u;
  return (u16)((u + 0x7FFFu + ((u >> 16) & 1u)) >> 16);
}

__device__ __forceinline__ float b2f(u16 u) {
  union { unsigned u; float f; } v; v.u = ((unsigned)u) << 16;
  return v.f;
}

// packed-bf16 dword helpers: low element = low u16, high element = high u16
__device__ __forceinline__ float blo(unsigned w) {
  union { unsigned u; float f; } v; v.u = w << 16;
  return v.f;
}
__device__ __forceinline__ float bhi(unsigned w) {
  union { unsigned u; float f; } v; v.u = w & 0xFFFF0000u;
  return v.f;
}

__device__ __forceinline__ float gelu_exact(float x) {
  return 0.5f * x * (1.f + erff(x * 0.70710678118654752440f));
}

__device__ __forceinline__ unsigned pack2(float a, float b) {
  return (unsigned)f2b(a) | ((unsigned)f2b(b) << 16);
}

// truncating pack of two f32 -> two bf16 in one v_perm
__device__ __forceinline__ unsigned permpack(float p0, float p1) {
  return __builtin_amdgcn_perm(__float_as_uint(p1), __float_as_uint(p0), 0x07060302u);
}

// ------------- fat kernel: weight transpose-convert (blocks 0..611) + LN1 (612..2659) -------------
__global__ __launch_bounds__(256) void tcln_kernel(
    const float* __restrict__ p0, const float* __restrict__ p1,
    const float* __restrict__ p2, const float* __restrict__ p3,
    const float* __restrict__ p4, const float* __restrict__ p5,
    const float* __restrict__ wknn,
    u16* __restrict__ o0, u16* __restrict__ o1, u16* __restrict__ o2,
    u16* __restrict__ o3, u16* __restrict__ o4, u16* __restrict__ o5,
    u16* __restrict__ wcT,
    const float* __restrict__ x, const float* __restrict__ g,
    const float* __restrict__ bia, u16* __restrict__ nx) {
  __shared__ u16 L[64][66];
  int t = blockIdx.x, tid = threadIdx.x;
  if (t >= 612) {
    // ---- LN1: one wave per row ----
    int wave = tid >> 6, lane = tid & 63;
    int row = (t - 612) * 4 + wave;
    const float* xr = x + (size_t)row * 384;
    float v[6];
    float s = 0.f;
#pragma unroll
    for (int j = 0; j < 6; j++) { v[j] = xr[lane + 64 * j]; s += v[j]; }
#pragma unroll
    for (int off = 32; off > 0; off >>= 1) s += __shfl_xor(s, off);
    float mu = s * (1.f / 384.f);
    float ss = 0.f;
#pragma unroll
    for (int j = 0; j < 6; j++) { float d = v[j] - mu; ss += d * d; }
#pragma unroll
    for (int off = 32; off > 0; off >>= 1) ss += __shfl_xor(ss, off);
    float rstd = rsqrtf(ss * (1.f / 384.f) + 1e-5f);
    u16* orow = nx + (size_t)row * 384;
#pragma unroll
    for (int j = 0; j < 6; j++) {
      int d = lane + 64 * j;
      orow[d] = f2b((v[j] - mu) * rstd * g[d] + bia[d]);
    }
    return;
  }
  if (t >= 540) {
    t -= 540;                       // wcT: 6 k-tiles x 12 j-tiles
    int tk = t / 12, tn = t % 12;
    int k0 = tk * 64, j0 = tn * 64;
#pragma unroll
    for (int i = 0; i < 4; i++) {
      int c = tid + 256 * i;
      int r = c >> 4, c4 = (c & 15) * 4;
      floatx4 v;
      if (j0 < 384) {
        v = *(const floatx4*)(wknn + (size_t)(k0 + r) * 384 + j0 + c4);
      } else {
        floatx4 a = *(const floatx4*)(wknn + (size_t)(384 + k0 + r) * 384 + (j0 - 384) + c4);
        floatx4 b = *(const floatx4*)(wknn + (size_t)(k0 + r) * 384 + (j0 - 384) + c4);
        v = a - b;
      }
      *(unsigned*)&L[r][c4]     = pack2(v[0], v[1]);
      *(unsigned*)&L[r][c4 + 2] = pack2(v[2], v[3]);
    }
    __syncthreads();
#pragma unroll
    for (int i = 0; i < 2; i++) {
      int c = tid + 256 * i;
      int nn = c >> 3, k8 = (c & 7) * 8;
      sh8u pk;
#pragma unroll
      for (int j = 0; j < 8; j++) pk.u[j] = L[k8 + j][nn];
      *(short8*)(wcT + (size_t)(j0 + nn) * 384 + k0 + k8) = pk.v;
    }
    return;
  }
  const float* src; u16* dst; int Kd, Nd, tk, tn;
  if      (t < 108) { src = p0; dst = o0; Kd = 384;  Nd = 1152; tk = t / 18; tn = t % 18; }
  else if (t < 144) { src = p1; dst = o1; Kd = 384;  Nd = 384;  t -= 108; tk = t / 6;  tn = t % 6; }
  else if (t < 216) { src = p2; dst = o2; Kd = 768;  Nd = 384;  t -= 144; tk = t / 6;  tn = t % 6; }
  else if (t < 252) { src = p3; dst = o3; Kd = 384;  Nd = 384;  t -= 216; tk = t / 6;  tn = t % 6; }
  else if (t < 396) { src = p4; dst = o4; Kd = 384;  Nd = 1536; t -= 252; tk = t / 24; tn = t % 24; }
  else              { src = p5; dst = o5; Kd = 1536; Nd = 384;  t -= 396; tk = t / 6;  tn = t % 6; }
  int k0 = tk * 64, n0 = tn * 64;
#pragma unroll
  for (int i = 0; i < 4; i++) {
    int c = tid + 256 * i;
    int r = c >> 4, c4 = (c & 15) * 4;
    floatx4 v = *(const floatx4*)(src + (size_t)(k0 + r) * Nd + n0 + c4);
    *(unsigned*)&L[r][c4]     = pack2(v[0], v[1]);
    *(unsigned*)&L[r][c4 + 2] = pack2(v[2], v[3]);
  }
  __syncthreads();
#pragma unroll
  for (int i = 0; i < 2; i++) {
    int c = tid + 256 * i;
    int nn = c >> 3, k8 = (c & 7) * 8;
    sh8u pk;
#pragma unroll
    for (int j = 0; j < 8; j++) pk.u[j] = L[k8 + j][nn];
    *(short8*)(dst + (size_t)(n0 + nn) * Kd + k0 + k8) = pk.v;
  }
}

// ---------------- LayerNorm (bf16 in -> bf16 out), one wave per row of 384 ----------------
__global__ __launch_bounds__(256) void lnb_kernel(const u16* __restrict__ x,
                                                  const float* __restrict__ g,
                                                  const float* __restrict__ bia,
                                                  u16* __restrict__ out) {
  int wave = threadIdx.x >> 6, lane = threadIdx.x & 63;
  int row = blockIdx.x * 4 + wave;
  const u16* xr = x + (size_t)row * 384;
  float v[6];
  float s = 0.f;
#pragma unroll
  for (int j = 0; j < 6; j++) { v[j] = b2f(xr[lane + 64 * j]); s += v[j]; }
#pragma unroll
  for (int off = 32; off > 0; off >>= 1) s += __shfl_xor(s, off);
  float mu = s * (1.f / 384.f);
  float ss = 0.f;
#pragma unroll
  for (int j = 0; j < 6; j++) { float d = v[j] - mu; ss += d * d; }
#pragma unroll
  for (int off = 32; off > 0; off >>= 1) ss += __shfl_xor(ss, off);
  float rstd = rsqrtf(ss * (1.f / 384.f) + 1e-5f);
  u16* orow = out + (size_t)row * 384;
#pragma unroll
  for (int j = 0; j < 6; j++) {
    int d = lane + 64 * j;
    orow[d] = f2b((v[j] - mu) * rstd * g[d] + bia[d]);
  }
}

// ---------------- gemm64: 64Mx128N tile, BK=64, reg-prefetch dbuf ----------------
// EPI: 3 gelu(+bias) -> bf16 | 4 gate -> bf16 | 7 +bias + bf16-resid -> f32
//      8 fused qkv+GB: col<1152 -> qkv (Q pre-scale, V^T scatter), else GBb bf16
template <int EPI>
__global__ __launch_bounds__(256) void gemm64_kernel(
    const u16* __restrict__ A0, const u16* __restrict__ A1, int Ksplit,
    const u16* __restrict__ BwT, const u16* __restrict__ BwT2, int N, int K,
    const float* __restrict__ bias,
    float* __restrict__ outF, u16* __restrict__ outB, u16* __restrict__ outB2,
    const u16* __restrict__ eA16, const u16* __restrict__ eK16,
    const float* __restrict__ eX, u16* __restrict__ outV) {
  __shared__ u16 As[64][72];
  __shared__ u16 Bs[128][72];
  int tid = threadIdx.x;
  int lane = tid & 63, w = tid >> 6, quad = lane >> 4, l16 = lane & 15;
  int n0 = blockIdx.x * 128, m0 = blockIdx.y * 64;
  int ra = tid >> 3, ca = (tid & 7) * 8;
  const u16* Bsrc = BwT;
  int nbase = n0;
  if (EPI == 8 && n0 >= 1152) { Bsrc = BwT2; nbase = n0 - 1152; }
  floatx4 acc[4][2];
#pragma unroll
  for (int i = 0; i < 4; i++)
#pragma unroll
    for (int j = 0; j < 2; j++) acc[i][j] = zero4();

  short8 pa[2], pb[4];
  auto loadAB = [&](int k0) {
    const u16* Ap;
    int kk, sA;
    if (k0 < Ksplit) { Ap = A0; kk = k0; sA = Ksplit; }
    else             { Ap = A1; kk = k0 - Ksplit; sA = K - Ksplit; }
    pa[0] = *(const short8*)(Ap + (size_t)(m0 + ra) * sA + kk + ca);
    pa[1] = *(const short8*)(Ap + (size_t)(m0 + ra + 32) * sA + kk + ca);
#pragma unroll
    for (int i = 0; i < 4; i++)
      pb[i] = *(const short8*)(Bsrc + (size_t)(nbase + ra + 32 * i) * K + k0 + ca);
  };
  loadAB(0);
  int iters = K >> 6;
  for (int kt = 0; kt < iters; kt++) {
    __syncthreads();
    *(short8*)&As[ra][ca] = pa[0];
    *(short8*)&As[ra + 32][ca] = pa[1];
#pragma unroll
    for (int i = 0; i < 4; i++) *(short8*)&Bs[ra + 32 * i][ca] = pb[i];
    __syncthreads();
    if (kt + 1 < iters) loadAB((kt + 1) * 64);
#pragma unroll
    for (int kh = 0; kh < 2; kh++) {
      short8 af[4], bfr[2];
#pragma unroll
      for (int mt = 0; mt < 4; mt++)
        af[mt] = *(const short8*)&As[mt * 16 + l16][kh * 32 + quad * 8];
#pragma unroll
      for (int nt = 0; nt < 2; nt++)
        bfr[nt] = *(const short8*)&Bs[w * 32 + nt * 16 + l16][kh * 32 + quad * 8];
#pragma unroll
      for (int mt = 0; mt < 4; mt++)
#pragma unroll
        for (int nt = 0; nt < 2; nt++)
          acc[mt][nt] = mfma16(af[mt], bfr[nt], acc[mt][nt]);
    }
  }

#pragma unroll
  for (int mt = 0; mt < 4; mt++)
#pragma unroll
    for (int nt = 0; nt < 2; nt++) {
      int col = n0 + w * 32 + nt * 16 + l16;
      int row0 = m0 + mt * 16 + quad * 4;
      if (EPI == 8) {
        if (col < 1152) {
          float sc = (col < 384) ? 0.18033688011112042f : 1.f;  // Q * 0.125*log2(e)
          sh4u pk;
#pragma unroll
          for (int r = 0; r < 4; r++) {
            u16 bv = f2b(acc[mt][nt][r] * sc);
            outB[(size_t)(row0 + r) * 1152 + col] = bv;
            pk.u[r] = bv;
          }
          if (col >= 768) {
            int b = row0 >> 11, n = row0 & 2047;
            int hd = col - 768;
            *(sh4v*)(outV + ((size_t)(b * 6 + (hd >> 6)) * 64 + (hd & 63)) * 2048 + n) = pk.v;
          }
        } else {
#pragma unroll
          for (int r = 0; r < 4; r++)
            outB2[(size_t)(row0 + r) * 768 + (col - 1152)] = f2b(acc[mt][nt][r]);
        }
      } else {
#pragma unroll
        for (int r = 0; r < 4; r++) {
          size_t rc = (size_t)(row0 + r) * N + col;
          float v = acc[mt][nt][r];
          if (EPI == 3) {
            outB[rc] = f2b(gelu_exact(v + bias[col]));
          } else if (EPI == 4) {
            float gte = 1.f / (1.f + hexp2(-1.44269504088896f * (v + bias[col])));
            float fu = (1.f - gte) * b2f(eA16[rc]) + gte * b2f(eK16[rc]);
            outB[rc] = f2b(eX[rc] + fu);
          } else if (EPI == 7) {
            outF[rc] = v + bias[col] + b2f(eA16[rc]);
          }
        }
      }
    }
}

// ------- fat kernel: attention (blocks 0..767, 2 splits) + EdgeConv knn (768..2815) -------
// attn: 4 waves x 32 q-rows, 32x32 MFMA, P in-register via permpack + permlane32_swap,
//       inline VALU row-sum. LDS double-buffered K/V tiles, one barrier per kt.
//       key-split=2 (1024 keys/split): halves Q-refetch, OPb write, projc combine
//       traffic vs split=4; same per-thread state (VGPR/occupancy unchanged).
__global__ __launch_bounds__(256) void attnknn_kernel(
    const u16* __restrict__ qkv, const u16* __restrict__ Vt,
    u16* __restrict__ OPb, float* __restrict__ LS,
    const u16* __restrict__ GBb, const int* __restrict__ kidx,
    const float* __restrict__ bknn, u16* __restrict__ knn_bf) {
  __shared__ u16 Ks[2][64][72];    // K tile [key][dim], double-buffered
  __shared__ u16 Vts[2][64][72];   // V^T tile [dim][key], double-buffered
  int bid = blockIdx.x, tid = threadIdx.x;
  int lane = tid & 63, w = tid >> 6;
  if (bid >= 768) {
    // ---- EdgeConv gather + max over K=8, then lrelu once (lrelu monotone, base k-invariant) ----
    int row = (bid - 768) * 4 + w;  // 0..8191
    int b = row >> 11, n = row & 2047;
    // lane element map: e0..e3 = 4*lane.. (dwords 2*lane,2*lane+1), e4,e5 = 256+2*lane (dword 128+lane)
    const unsigned* browp = (const unsigned*)(GBb + (size_t)row * 768 + 384);
    uint2v bw01 = *(const uint2v*)(browp + 2 * lane);
    unsigned bw2 = browp[128 + lane];
    floatx4 bk4 = *(const floatx4*)(bknn + 4 * lane);
    float bk40 = bknn[256 + 2 * lane], bk41 = bknn[256 + 2 * lane + 1];
    int gi[8];
#pragma unroll
    for (int kk = 0; kk < 8; kk++) gi[kk] = kidx[(b * 8 + kk) * 2048 + n];
    float mx[6];
#pragma unroll
    for (int e = 0; e < 6; e++) mx[e] = -1e30f;
#pragma unroll
    for (int kk = 0; kk < 8; kk++) {
      const unsigned* gp = (const unsigned*)(GBb + (size_t)gi[kk] * 768);
      uint2v g01 = *(const uint2v*)(gp + 2 * lane);
      unsigned g2 = gp[128 + lane];
      mx[0] = fmaxf(mx[0], blo(g01[0]));
      mx[1] = fmaxf(mx[1], bhi(g01[0]));
      mx[2] = fmaxf(mx[2], blo(g01[1]));
      mx[3] = fmaxf(mx[3], bhi(g01[1]));
      mx[4] = fmaxf(mx[4], blo(g2));
      mx[5] = fmaxf(mx[5], bhi(g2));
    }
    float vv[6];
    vv[0] = mx[0] + blo(bw01[0]) + bk4[0];
    vv[1] = mx[1] + bhi(bw01[0]) + bk4[1];
    vv[2] = mx[2] + blo(bw01[1]) + bk4[2];
    vv[3] = mx[3] + bhi(bw01[1]) + bk4[3];
    vv[4] = mx[4] + blo(bw2) + bk40;
    vv[5] = mx[5] + bhi(bw2) + bk41;
#pragma unroll
    for (int e = 0; e < 6; e++) vv[e] = fmaxf(vv[e], 0.2f * vv[e]);
    unsigned* op = (unsigned*)(knn_bf + (size_t)row * 384);
    uint2v ow;
    ow[0] = pack2(vv[0], vv[1]);
    ow[1] = pack2(vv[2], vv[3]);
    *(uint2v*)(op + 2 * lane) = ow;
    op[128 + lane] = pack2(vv[4], vv[5]);
    return;
  }
  // XCD-aware swizzle: the 16 q-tile blocks sharing one (b,h,split) K/V panel land on one XCD
  int vb = (bid & 7) * 96 + (bid >> 3);   // bijective: 768 = 8*96
  int split = vb / 384;                    // 0..1
  int rr = vb - split * 384;
  int bh = rr >> 4, b = bh / 6, h = bh % 6;
  int q0 = (rr & 15) * 128;
  int ql = lane & 31, h5 = lane >> 5;
  const u16* qbase = qkv + (size_t)b * 2048 * 1152 + h * 64;
  const u16* kbase = qbase + 384 + (size_t)split * 1024 * 1152;
  const u16* vtb = Vt + (size_t)bh * 64 * 2048 + split * 1024;
  int qrow = q0 + w * 32 + ql;
  // Q B-fragments: lane holds Q[qrow][16*s + 8*h5 + 0..7]  (Q pre-scaled by 0.125*log2e)
  short8 qB[4];
#pragma unroll
  for (int s = 0; s < 4; s++)
    qB[s] = *(const short8*)(qbase + (size_t)qrow * 1152 + s * 16 + h5 * 8);
  floatx16 O[2];
  O[0] = zero16(); O[1] = zero16();
  float accLs = 0.f;  // per-lane partial row-sum (16-key subset per t; halves combined at epilogue)

  int rb = tid >> 3, c8 = (tid & 7) * 8;
  short8 rk[2], rv[2];
  rk[0] = *(const short8*)(kbase + (size_t)rb * 1152 + c8);
  rk[1] = *(const short8*)(kbase + (size_t)(rb + 32) * 1152 + c8);
  rv[0] = *(const short8*)(vtb + (size_t)rb * 2048 + c8);
  rv[1] = *(const short8*)(vtb + (size_t)(rb + 32) * 2048 + c8);

  int cur = 0;
  for (int kt = 0; kt < 16; kt++) {
    // write this tile into buf[cur]; safe vs readers of buf[cur^1] (previous iter)
    *(short8*)&Ks[cur][rb][c8] = rk[0];
    *(short8*)&Ks[cur][rb + 32][c8] = rk[1];
    *(short8*)&Vts[cur][rb][c8] = rv[0];
    *(short8*)&Vts[cur][rb + 32][c8] = rv[1];
    __syncthreads();  // single barrier per kt: tile visible to all waves
    if (kt < 15) {
      int key0 = (kt + 1) * 64;
      rk[0] = *(const short8*)(kbase + (size_t)(key0 + rb) * 1152 + c8);
      rk[1] = *(const short8*)(kbase + (size_t)(key0 + rb + 32) * 1152 + c8);
      rv[0] = *(const short8*)(vtb + (size_t)rb * 2048 + key0 + c8);
      rv[1] = *(const short8*)(vtb + (size_t)(rb + 32) * 2048 + key0 + c8);
    }
    // per key-half t: S^T (32 keys x 32 q) in registers, exp2 inline, pack, then PV
#pragma unroll
    for (int t = 0; t < 2; t++) {
      floatx16 st = zero16();
#pragma unroll
      for (int s = 0; s < 4; s++) {
        short8 aK = *(const short8*)&Ks[cur][32 * t + ql][16 * s + 8 * h5];
        st = mfma32(aK, qB[s], st);
      }
      // key(r) = 32t + (r&3) + 8*(r>>2) + 4*h5; W[j] packs keys (koff(j), koff(j)+1),
      // koff = {0,2,8,10,16,18,24,26}. Row-sum accumulated inline (no e[] array).
      unsigned W[8];
#pragma unroll
      for (int j = 0; j < 8; j++) {
        float e0 = hexp2(st[2 * j]), e1 = hexp2(st[2 * j + 1]);
        accLs += e0 + e1;
        W[j] = permpack(e0, e1);
      }
      // PV: two 16-key chunks per t. b-frag words via permlane32_swap of (+8)-offset pairs.
#pragma unroll
      for (int c = 0; c < 2; c++) {
        int kk = 2 * t + c;
        uint2v s0 = __builtin_amdgcn_permlane32_swap(W[4 * c], W[4 * c + 2], false, false);
        uint2v s1 = __builtin_amdgcn_permlane32_swap(W[4 * c + 1], W[4 * c + 3], false, false);
        sh8w pb_;
        pb_.w[0] = s0[0];
        pb_.w[1] = s1[0];
        pb_.w[2] = s0[1];
        pb_.w[3] = s1[1];
        short8 aV0 = *(const short8*)&Vts[cur][ql][16 * kk + 8 * h5];
        short8 aV1 = *(const short8*)&Vts[cur][32 + ql][16 * kk + 8 * h5];
        O[0] = mfma32(aV0, pb_.v, O[0]);
        O[1] = mfma32(aV1, pb_.v, O[1]);
      }
    }
    cur ^= 1;
  }
  // epilogue: unnormalized bf16 partials + f32 row-sum
  // O^T layout: q = ql, dim = 32*d + (r&3) + 8*(r>>2) + 4*h5
  u16* orow = OPb + (size_t)split * 8192 * 384 + (size_t)(b * 2048 + qrow) * 384 + h * 64;
#pragma unroll
  for (int d = 0; d < 2; d++)
#pragma unroll
    for (int rq = 0; rq < 4; rq++) {
      sh4u pk;
#pragma unroll
      for (int r3 = 0; r3 < 4; r3++) pk.u[r3] = f2b(O[d][4 * rq + r3]);
      *(sh4v*)(orow + 32 * d + 8 * rq + 4 * h5) = pk.v;
    }
  // combine h5 halves: lane<32 adds partner (lane+32)'s partial via permlane32_swap out1
  uint2v sw = __builtin_amdgcn_permlane32_swap(__float_as_uint(accLs), __float_as_uint(accLs),
                                               false, false);
  if (lane < 32) LS[split * 8192 + b * 2048 + qrow] = accLs + __uint_as_float(sw[1]);
}

// ---------------- proj: 64Mx128N GEMM on unnormalized 2-split sum, normalize in epilogue ----------------
__global__ __launch_bounds__(256) void projc_kernel(
    const u16* __restrict__ OPb, const float* __restrict__ LS,
    const u16* __restrict__ BwT, const float* __restrict__ bias,
    u16* __restrict__ outB) {
  __shared__ u16 As[64][72];
  __shared__ u16 Bs[128][72];
  int tid = threadIdx.x;
  int lane = tid & 63, w = tid >> 6, quad = lane >> 4, l16 = lane & 15;
  int n0 = blockIdx.x * 128, m0 = blockIdx.y * 64;
  int ra = tid >> 3, ca = (tid & 7) * 8;
  const size_t SP = (size_t)8192 * 384;
  floatx4 acc[4][2];
#pragma unroll
  for (int i = 0; i < 4; i++)
#pragma unroll
    for (int j = 0; j < 2; j++) acc[i][j] = zero4();

  short8 pa[2], pb[4];
  auto loadAB = [&](int k0) {
#pragma unroll
    for (int i = 0; i < 2; i++) {
      const u16* p = OPb + (size_t)(m0 + ra + 32 * i) * 384 + k0 + ca;
      sh8u a0, a1, pk;
      a0.v = *(const short8*)p;
      a1.v = *(const short8*)(p + SP);
#pragma unroll
      for (int j = 0; j < 8; j++)
        pk.u[j] = f2b(b2f(a0.u[j]) + b2f(a1.u[j]));
      pa[i] = pk.v;
    }
#pragma unroll
    for (int i = 0; i < 4; i++)
      pb[i] = *(const short8*)(BwT + (size_t)(n0 + ra + 32 * i) * 384 + k0 + ca);
  };
  loadAB(0);
  for (int kt = 0; kt < 6; kt++) {
    __syncthreads();
    *(short8*)&As[ra][ca] = pa[0];
    *(short8*)&As[ra + 32][ca] = pa[1];
#pragma unroll
    for (int i = 0; i < 4; i++) *(short8*)&Bs[ra + 32 * i][ca] = pb[i];
    __syncthreads();
    if (kt < 5) loadAB((kt + 1) * 64);
#pragma unroll
    for (int kh = 0; kh < 2; kh++) {
      short8 af[4], bfr[2];
#pragma unroll
      for (int mt = 0; mt < 4; mt++)
        af[mt] = *(const short8*)&As[mt * 16 + l16][kh * 32 + quad * 8];
#pragma unroll
      for (int nt = 0; nt < 2; nt++)
        bfr[nt] = *(const short8*)&Bs[w * 32 + nt * 16 + l16][kh * 32 + quad * 8];
#pragma unroll
      for (int mt = 0; mt < 4; mt++)
#pragma unroll
        for (int nt = 0; nt < 2; nt++)
          acc[mt][nt] = mfma16(af[mt], bfr[nt], acc[mt][nt]);
    }
  }
#pragma unroll
  for (int mt = 0; mt < 4; mt++) {
    int row0 = m0 + mt * 16 + quad * 4;
    float rl[4];
#pragma unroll
    for (int r = 0; r < 4; r++) {
      int gr = row0 + r;
      rl[r] = 1.f / (LS[gr] + LS[8192 + gr]);
    }
#pragma unroll
    for (int nt = 0; nt < 2; nt++) {
      int col = n0 + w * 32 + nt * 16 + l16;
#pragma unroll
      for (int r = 0; r < 4; r++)
        outB[(size_t)(row0 + r) * 384 + col] = f2b(acc[mt][nt][r] * rl[r] + bias[col]);
    }
  }
}

// ---------------- launch ----------------
extern "C" void kernel_launch(void* const* d_in, const int* in_sizes, int n_in,
                              void* d_out, int out_size, void* d_ws, size_t ws_size,
                              hipStream_t stream) {
  const float* x    = (const float*)d_in[0];
  const int* kidx   = (const int*)d_in[1];
  const float* ln1g = (const float*)d_in[2];
  const float* ln1b = (const float*)d_in[3];
  const float* wqkv = (const float*)d_in[4];
  const float* wproj= (const float*)d_in[5];
  const float* bproj= (const float*)d_in[6];
  const float* wknn = (const float*)d_in[7];
  const float* bknn = (const float*)d_in[8];
  const float* wg1  = (const float*)d_in[9];
  const float* bg1  = (const float*)d_in[10];
  const float* wg2  = (const float*)d_in[11];
  const float* bg2  = (const float*)d_in[12];
  const float* ln2g = (const float*)d_in[13];
  const float* ln2b = (const float*)d_in[14];
  const float* wfc1 = (const float*)d_in[15];
  const float* bfc1 = (const float*)d_in[16];
  const float* wfc2 = (const float*)d_in[17];
  const float* bfc2 = (const float*)d_in[18];
  float* out = (float*)d_out;

  const int M = 8192;
  char* ws = (char*)d_ws;
  size_t off = 0;
  auto alloc = [&](size_t bytes) -> char* {
    char* p = ws + off;
    off += (bytes + 255) & ~(size_t)255;
    return p;
  };
  u16* nx_bf    = (u16*)alloc((size_t)M * 384 * 2);
  u16* qkv_bf   = (u16*)alloc((size_t)M * 1152 * 2);   // + attn_bf reused as h_bf
  u16* attn_bf  = (u16*)alloc((size_t)M * 384 * 2);
  u16* GBb      = (u16*)alloc((size_t)M * 768 * 2);    // [G | base] bf16
  u16* knn_bf   = (u16*)alloc((size_t)M * 384 * 2);
  u16* x2b      = (u16*)alloc((size_t)M * 384 * 2);
  u16* t1_bf    = (u16*)alloc((size_t)M * 384 * 2);
  u16* nx2_bf   = (u16*)alloc((size_t)M * 384 * 2);
  u16* Vt_b     = (u16*)alloc((size_t)24 * 64 * 2048 * 2);
  u16* OPb      = (u16*)alloc((size_t)2 * M * 384 * 2);  // attn split partials (bf16, 2 splits)
  float* LS     = (float*)alloc((size_t)2 * M * 4);
  u16* wqkvT    = (u16*)alloc((size_t)1152 * 384 * 2);
  u16* wprojT   = (u16*)alloc(384 * 384 * 2);
  u16* wcT      = (u16*)alloc((size_t)768 * 384 * 2);
  u16* wg1T     = (u16*)alloc((size_t)384 * 768 * 2);
  u16* wg2T     = (u16*)alloc(384 * 384 * 2);
  u16* wfc1T    = (u16*)alloc((size_t)1536 * 384 * 2);
  u16* wfc2T    = (u16*)alloc((size_t)384 * 1536 * 2);
  u16* h_bf     = qkv_bf;  // 8192x1536 bf16 over dead qkv(18.9MB)+attn_bf(6.3MB) regions

  // weight prep + LN1 (one fat launch)
  tcln_kernel<<<2660, 256, 0, stream>>>(wqkv, wproj, wg1, wg2, wfc1, wfc2, wknn,
                                        wqkvT, wprojT, wg1T, wg2T, wfc1T, wfc2T, wcT,
                                        x, ln1g, ln1b, nx_bf);
  // fused qkv + GB: [qkv | GBb] = nx @ [wqkvT | wcT]  (1920 blocks)
  gemm64_kernel<8><<<dim3(15, 128), 256, 0, stream>>>(nx_bf, nx_bf, 384, wqkvT, wcT, 1920, 384,
                                                      nullptr, nullptr, qkv_bf, GBb,
                                                      nullptr, nullptr, nullptr, Vt_b);
  // attention (key-split=2, 32x32 MFMA + permlane P, LDS dbuf 1-barrier) + knn gather-max
  attnknn_kernel<<<2816, 256, 0, stream>>>(qkv_bf, Vt_b, OPb, LS,
                                           GBb, kidx, bknn, knn_bf);
  // proj: combine(OP0,OP1) @ wprojT, normalize+bias in epilogue  (384 blocks)
  projc_kernel<<<dim3(3, 128), 256, 0, stream>>>(OPb, LS, wprojT, bproj, attn_bf);
  // gate hidden: gelu([attn|knn] @ w_g1 + b_g1) -> bf16  (384 blocks)
  gemm64_kernel<3><<<dim3(3, 128), 256, 0, stream>>>(attn_bf, knn_bf, 384, wg1T, nullptr, 384, 768,
                                                     bg1, nullptr, t1_bf, nullptr,
                                                     nullptr, nullptr, nullptr, nullptr);
  // gate + fuse + residual: x2b = bf16(x + (1-g)*attn + g*knn)  (384 blocks)
  gemm64_kernel<4><<<dim3(3, 128), 256, 0, stream>>>(t1_bf, t1_bf, 384, wg2T, nullptr, 384, 384,
                                                     bg2, nullptr, x2b, nullptr,
                                                     attn_bf, knn_bf, x, nullptr);
  // LN2 (bf16 in)
  lnb_kernel<<<2048, 256, 0, stream>>>(x2b, ln2g, ln2b, nx2_bf);
  // fc1: gelu(nx2 @ w_fc1 + b_fc1) -> bf16  (1536 blocks)
  gemm64_kernel<3><<<dim3(12, 128), 256, 0, stream>>>(nx2_bf, nx2_bf, 384, wfc1T, nullptr, 1536, 384,
                                                      bfc1, nullptr, h_bf, nullptr,
                                                      nullptr, nullptr, nullptr, nullptr);
  // fc2: out = x2 + h @ w_fc2 + b_fc2  (384 blocks)
  gemm64_kernel<7><<<dim3(3, 128), 256, 0, stream>>>(h_bf, h_bf, 1536, wfc2T, nullptr, 384, 1536,
                                                     bfc2, out, nullptr, nullptr,
                                                     x2b, nullptr, nullptr, nullptr);
  (void)in_sizes; (void)n_in; (void)out_size; (void)ws_size;
}